// Round 1
// baseline (1715.595 us; speedup 1.0000x reference)
//
#include <hip/hip_runtime.h>

// GCN classifier: 4 graph-conv layers (H=64) + mean-pool + linear head.
// Inputs: src(E i32), dst(E i32), graph_ids(N i32 sorted), n_graphs(1),
//         W1(1x64), b1(64), W2(64x64), b2, W3(64x64), b3, W4(64x64), b4,
//         Wc(64x10), bc(10)
// Output: concat(hg[ng*64], logits[ng*10]) fp32.

__global__ void deg_kernel(const int* __restrict__ src, const int* __restrict__ dst,
                           float* __restrict__ in_deg, float* __restrict__ out_deg, int E) {
    int stride = gridDim.x * blockDim.x;
    for (int e = blockIdx.x * blockDim.x + threadIdx.x; e < E; e += stride) {
        atomicAdd(&in_deg[dst[e]], 1.0f);
        atomicAdd(&out_deg[src[e]], 1.0f);
    }
}

__global__ void norm_kernel(const float* __restrict__ in_deg, const float* __restrict__ out_deg,
                            float* __restrict__ norm_src, float* __restrict__ norm_dst, int N) {
    int n = blockIdx.x * blockDim.x + threadIdx.x;
    if (n < N) {
        norm_src[n] = rsqrtf(fmaxf(out_deg[n], 1.0f));
        norm_dst[n] = rsqrtf(fmaxf(in_deg[n], 1.0f));
    }
}

// Layer 1 aggregation: h is N x 1 (h = in_deg), so scatter a scalar per edge.
__global__ void scatter1_kernel(const int* __restrict__ src, const int* __restrict__ dst,
                                const float* __restrict__ in_deg, const float* __restrict__ norm_src,
                                float* __restrict__ agg0, int E) {
    int stride = gridDim.x * blockDim.x;
    for (int e = blockIdx.x * blockDim.x + threadIdx.x; e < E; e += stride) {
        int s = src[e];
        atomicAdd(&agg0[dst[e]], in_deg[s] * norm_src[s]);
    }
}

// Layer 1 dense: out[n][j] = relu(agg0[n]*norm_dst[n]*W1[j] + b1[j]) * norm_src[n]
__global__ void dense1_kernel(const float* __restrict__ agg0, const float* __restrict__ norm_dst,
                              const float* __restrict__ norm_src, const float* __restrict__ W1,
                              const float* __restrict__ b1, float* __restrict__ out, int N) {
    int stride = gridDim.x * blockDim.x;
    int total = N * 64;
    for (int i = blockIdx.x * blockDim.x + threadIdx.x; i < total; i += stride) {
        int n = i >> 6, j = i & 63;
        float a = agg0[n] * norm_dst[n];
        float y = fmaxf(fmaf(a, W1[j], b1[j]), 0.0f);
        out[i] = y * norm_src[n];
    }
}

// Edge scatter, 64 features wide: one wave per edge, lane = feature index.
__global__ void scatter64_kernel(const int* __restrict__ src, const int* __restrict__ dst,
                                 const float* __restrict__ x, float* __restrict__ agg, int E) {
    int lane = threadIdx.x & 63;
    int wid = (blockIdx.x * blockDim.x + threadIdx.x) >> 6;
    int nw = (gridDim.x * blockDim.x) >> 6;
    for (int e = wid; e < E; e += nw) {
        int s = src[e];
        int d = dst[e];
        float v = x[(size_t)s * 64 + lane];
        atomicAdd(&agg[(size_t)d * 64 + lane], v);
    }
}

// Fused: v = agg[n]*norm_dst[n]; y = relu(v @ W + b); out = y * (apply_src ? norm_src[n] : 1)
__global__ void dense_kernel(const float* __restrict__ agg, const float* __restrict__ norm_dst,
                             const float* __restrict__ norm_src, const float* __restrict__ W,
                             const float* __restrict__ b, float* __restrict__ out, int N, int apply_src) {
    __shared__ float Wsh[64 * 64];
    for (int i = threadIdx.x; i < 64 * 64; i += blockDim.x) Wsh[i] = W[i];
    __syncthreads();
    int lane = threadIdx.x & 63;
    int grp = threadIdx.x >> 6;
    int gpb = blockDim.x >> 6;          // wave-groups per block
    int ngrp = gridDim.x * gpb;
    float bj = b[lane];
    for (int n = blockIdx.x * gpb + grp; n < N; n += ngrp) {
        float v = agg[(size_t)n * 64 + lane] * norm_dst[n];
        float acc = bj;
        #pragma unroll
        for (int k = 0; k < 64; ++k) {
            float vk = __shfl(v, k, 64);
            acc = fmaf(vk, Wsh[k * 64 + lane], acc);
        }
        acc = fmaxf(acc, 0.0f);
        if (apply_src) acc *= norm_src[n];
        out[(size_t)n * 64 + lane] = acc;
    }
}

// One block per graph: mean-pool h over the graph's (contiguous, sorted) node
// range, write hg row, then compute the 10 logits for that graph.
__global__ void pool_kernel(const float* __restrict__ h, const int* __restrict__ gid, int N,
                            const float* __restrict__ Wc, const float* __restrict__ bc,
                            float* __restrict__ out, int n_graphs) {
    int g = blockIdx.x;
    // lower_bound(g) and lower_bound(g+1) — uniform, done redundantly per thread
    int lo = 0, hi = N;
    while (lo < hi) { int mid = (lo + hi) >> 1; if (gid[mid] < g) lo = mid + 1; else hi = mid; }
    int start = lo;
    hi = N;
    while (lo < hi) { int mid = (lo + hi) >> 1; if (gid[mid] < g + 1) lo = mid + 1; else hi = mid; }
    int end = lo;
    int cnt = end - start;

    int lane = threadIdx.x & 63;
    int grp = threadIdx.x >> 6;         // 0..3
    float acc = 0.0f;
    for (int n = start + grp; n < end; n += 4) acc += h[(size_t)n * 64 + lane];

    __shared__ float sh[4][64];
    __shared__ float hrow[64];
    sh[grp][lane] = acc;
    __syncthreads();
    if (threadIdx.x < 64) {
        float s = sh[0][lane] + sh[1][lane] + sh[2][lane] + sh[3][lane];
        float m = s / fmaxf((float)cnt, 1.0f);
        hrow[lane] = m;
        out[(size_t)g * 64 + lane] = m;                 // hg
    }
    __syncthreads();
    if (threadIdx.x < 10) {
        int c = threadIdx.x;
        float acc2 = bc[c];
        #pragma unroll
        for (int j = 0; j < 64; ++j) acc2 = fmaf(hrow[j], Wc[j * 10 + c], acc2);
        out[(size_t)n_graphs * 64 + (size_t)g * 10 + c] = acc2;   // logits
    }
}

extern "C" void kernel_launch(void* const* d_in, const int* in_sizes, int n_in,
                              void* d_out, int out_size, void* d_ws, size_t ws_size,
                              hipStream_t stream) {
    const int*   src = (const int*)d_in[0];
    const int*   dst = (const int*)d_in[1];
    const int*   gid = (const int*)d_in[2];
    const float* W1  = (const float*)d_in[4];
    const float* b1  = (const float*)d_in[5];
    const float* W2  = (const float*)d_in[6];
    const float* b2  = (const float*)d_in[7];
    const float* W3  = (const float*)d_in[8];
    const float* b3  = (const float*)d_in[9];
    const float* W4  = (const float*)d_in[10];
    const float* b4  = (const float*)d_in[11];
    const float* Wc  = (const float*)d_in[12];
    const float* bc  = (const float*)d_in[13];

    int E  = in_sizes[0];
    int N  = in_sizes[2];
    int ng = out_size / 74;                 // 64 hg + 10 logits per graph

    float* ws       = (float*)d_ws;
    float* norm_src = ws;                   // N
    float* norm_dst = ws + N;               // N
    float* bufA     = ws + 2 * (size_t)N;   // 64N
    float* bufB     = bufA + 64 * (size_t)N;// 64N
    // aliases (only live before bufA/bufB are first fully written)
    float* in_deg   = bufA;                 // N
    float* out_deg  = bufA + N;             // N
    float* agg0     = bufB;                 // N

    float* out_f = (float*)d_out;

    // degrees + norms
    hipMemsetAsync(in_deg, 0, 2 * (size_t)N * sizeof(float), stream);
    deg_kernel<<<2048, 256, 0, stream>>>(src, dst, in_deg, out_deg, E);
    norm_kernel<<<(N + 255) / 256, 256, 0, stream>>>(in_deg, out_deg, norm_src, norm_dst, N);

    // layer 1 (scalar feature)
    hipMemsetAsync(agg0, 0, (size_t)N * sizeof(float), stream);
    scatter1_kernel<<<2048, 256, 0, stream>>>(src, dst, in_deg, norm_src, agg0, E);
    dense1_kernel<<<2048, 256, 0, stream>>>(agg0, norm_dst, norm_src, W1, b1, bufA, N);

    // layer 2
    hipMemsetAsync(bufB, 0, 64 * (size_t)N * sizeof(float), stream);
    scatter64_kernel<<<2048, 256, 0, stream>>>(src, dst, bufA, bufB, E);
    dense_kernel<<<1024, 256, 0, stream>>>(bufB, norm_dst, norm_src, W2, b2, bufA, N, 1);

    // layer 3
    hipMemsetAsync(bufB, 0, 64 * (size_t)N * sizeof(float), stream);
    scatter64_kernel<<<2048, 256, 0, stream>>>(src, dst, bufA, bufB, E);
    dense_kernel<<<1024, 256, 0, stream>>>(bufB, norm_dst, norm_src, W3, b3, bufA, N, 1);

    // layer 4 (no norm_src on output; h kept for pooling)
    hipMemsetAsync(bufB, 0, 64 * (size_t)N * sizeof(float), stream);
    scatter64_kernel<<<2048, 256, 0, stream>>>(src, dst, bufA, bufB, E);
    dense_kernel<<<1024, 256, 0, stream>>>(bufB, norm_dst, norm_src, W4, b4, bufA, N, 0);

    // mean-pool + classifier head
    pool_kernel<<<ng, 256, 0, stream>>>(bufA, gid, N, Wc, bc, out_f, ng);
}

// Round 3
// 1149.361 us; speedup vs baseline: 1.4927x; 1.4927x over previous
//
#include <hip/hip_runtime.h>

// GCN classifier: CSR pull-based aggregation + fused GEMV per layer.
// Inputs: src(E i32), dst(E i32), graph_ids(N i32 sorted), n_graphs(1),
//         W1(1x64), b1(64), W2(64x64), b2, W3, b3, W4, b4, Wc(64x10), bc(10)
// Output: concat(hg[ng*64], logits[ng*10]) fp32.
// Workspace: ~8N+E ints + ~132N floats ≈ 61 MB.

// ---------- degree histogram (int atomics, once) ----------
__global__ void deg_kernel(const int* __restrict__ src, const int* __restrict__ dst,
                           int* __restrict__ in_deg, int* __restrict__ out_deg, int E) {
    int stride = gridDim.x * blockDim.x;
    for (int e = blockIdx.x * blockDim.x + threadIdx.x; e < E; e += stride) {
        atomicAdd(&in_deg[dst[e]], 1);
        atomicAdd(&out_deg[src[e]], 1);
    }
}

// norms + layer-1 pre-scaled feature xs = in_deg * norm_src
__global__ void norm_kernel(const int* __restrict__ in_deg, const int* __restrict__ out_deg,
                            float* __restrict__ norm_src, float* __restrict__ norm_dst,
                            float* __restrict__ xs, int N) {
    int n = blockIdx.x * blockDim.x + threadIdx.x;
    if (n < N) {
        float id = (float)in_deg[n];
        float od = (float)out_deg[n];
        float ns = rsqrtf(fmaxf(od, 1.0f));
        norm_src[n] = ns;
        norm_dst[n] = rsqrtf(fmaxf(id, 1.0f));
        xs[n] = id * ns;
    }
}

// ---------- 3-kernel exclusive prefix scan of in_deg -> row_ptr ----------
__global__ void scan_reduce(const int* __restrict__ vals, int* __restrict__ block_sums, int N) {
    int t = threadIdx.x, b = blockIdx.x;
    int base = b * 1024 + t * 4;
    int s = 0;
    #pragma unroll
    for (int k = 0; k < 4; ++k) { int i = base + k; if (i < N) s += vals[i]; }
    for (int d = 32; d > 0; d >>= 1) s += __shfl_down(s, d, 64);
    __shared__ int wsum[4];
    if ((t & 63) == 0) wsum[t >> 6] = s;
    __syncthreads();
    if (t == 0) block_sums[b] = wsum[0] + wsum[1] + wsum[2] + wsum[3];
}

// single block, 1024 threads: exclusive scan of block sums (NB <= 1024)
__global__ void scan_top(const int* __restrict__ block_sums, int* __restrict__ block_offs,
                         int NB, int* __restrict__ row_ptr, int N) {
    __shared__ int ts[1024];
    int t = threadIdx.x;
    int s = (t < NB) ? block_sums[t] : 0;
    ts[t] = s;
    __syncthreads();
    for (int d = 1; d < 1024; d <<= 1) {
        int x = (t >= d) ? ts[t - d] : 0;
        __syncthreads();
        ts[t] += x;
        __syncthreads();
    }
    block_offs[t] = ts[t] - s;                 // exclusive
    if (t == 1023) row_ptr[N] = ts[1023];      // total == E
}

// per-block scan + add offset; writes row_ptr[i] and cursor[i] (copy)
__global__ void scan_apply(const int* __restrict__ vals, const int* __restrict__ block_offs,
                           int* __restrict__ row_ptr, int* __restrict__ cursor, int N) {
    __shared__ int ts[256];
    int t = threadIdx.x, b = blockIdx.x;
    int base = b * 1024 + t * 4;
    int v[4]; int s = 0;
    #pragma unroll
    for (int k = 0; k < 4; ++k) { int i = base + k; v[k] = (i < N) ? vals[i] : 0; s += v[k]; }
    ts[t] = s;
    __syncthreads();
    for (int d = 1; d < 256; d <<= 1) {
        int x = (t >= d) ? ts[t - d] : 0;
        __syncthreads();
        ts[t] += x;
        __syncthreads();
    }
    int ex = block_offs[b] + ts[t] - s;        // exclusive prefix for index `base`
    #pragma unroll
    for (int k = 0; k < 4; ++k) {
        int i = base + k;
        if (i < N) { row_ptr[i] = ex; cursor[i] = ex; }
        ex += v[k];
    }
}

// scatter edges into CSR rows via per-row atomic cursor
__global__ void fill_kernel(const int* __restrict__ src, const int* __restrict__ dst,
                            int* __restrict__ cursor, int* __restrict__ csr_src, int E) {
    int stride = gridDim.x * blockDim.x;
    for (int e = blockIdx.x * blockDim.x + threadIdx.x; e < E; e += stride) {
        int p = atomicAdd(&cursor[dst[e]], 1);
        csr_src[p] = src[e];
    }
}

// ---------- layer 1 (scalar feature) ----------
// a_buf[n] = norm_dst[n] * sum_{incoming e} xs[src(e)]
__global__ void agg1_kernel(const int* __restrict__ row_ptr, const int* __restrict__ csr_src,
                            const float* __restrict__ xs, const float* __restrict__ norm_dst,
                            float* __restrict__ a_buf, int N) {
    int n = blockIdx.x * blockDim.x + threadIdx.x;
    if (n < N) {
        int s0 = row_ptr[n], s1 = row_ptr[n + 1];
        float a = 0.0f;
        for (int i = s0; i < s1; ++i) a += xs[csr_src[i]];
        a_buf[n] = a * norm_dst[n];
    }
}

// out[n][j] = relu(a*W1[j]+b1[j]) * norm_src[n]
__global__ void dense1_kernel(const float* __restrict__ a_buf, const float* __restrict__ norm_src,
                              const float* __restrict__ W1, const float* __restrict__ b1,
                              float* __restrict__ out, int N) {
    int stride = gridDim.x * blockDim.x;
    int total = N * 64;
    for (int i = blockIdx.x * blockDim.x + threadIdx.x; i < total; i += stride) {
        int n = i >> 6, j = i & 63;
        float y = fmaxf(fmaf(a_buf[n], W1[j], b1[j]), 0.0f);
        out[i] = y * norm_src[n];
    }
}

// ---------- fused pull-aggregate + GEMV + relu + norm, one wave per node ----------
__global__ void conv_fused(const int* __restrict__ row_ptr, const int* __restrict__ csr_src,
                           const float* __restrict__ x, const float* __restrict__ norm_dst,
                           const float* __restrict__ norm_src, const float* __restrict__ W,
                           const float* __restrict__ b, float* __restrict__ out,
                           int N, int apply_src) {
    __shared__ float Wsh[64 * 64];
    for (int i = threadIdx.x; i < 64 * 64; i += blockDim.x) Wsh[i] = W[i];
    __syncthreads();
    int lane = threadIdx.x & 63;
    int grp  = threadIdx.x >> 6;
    int gpb  = blockDim.x >> 6;
    int gw   = blockIdx.x * gpb + grp;
    int nw   = gridDim.x * gpb;
    float bj = b[lane];
    for (int n = gw; n < N; n += nw) {
        int s0 = row_ptr[n], s1 = row_ptr[n + 1];
        float acc = 0.0f;
        int i = s0;
        for (; i + 1 < s1; i += 2) {       // 2-deep MLP on the gathers
            int sa = csr_src[i], sb = csr_src[i + 1];
            float va = x[(size_t)sa * 64 + lane];
            float vb = x[(size_t)sb * 64 + lane];
            acc += va + vb;
        }
        if (i < s1) acc += x[(size_t)csr_src[i] * 64 + lane];
        float v = acc * norm_dst[n];
        float y = bj;
        #pragma unroll
        for (int k = 0; k < 64; ++k) {
            float vk = __shfl(v, k, 64);
            y = fmaf(vk, Wsh[k * 64 + lane], y);
        }
        y = fmaxf(y, 0.0f);
        if (apply_src) y *= norm_src[n];
        out[(size_t)n * 64 + lane] = y;
    }
}

// ---------- mean-pool + classifier head (one block per graph) ----------
__global__ void pool_kernel(const float* __restrict__ h, const int* __restrict__ gid, int N,
                            const float* __restrict__ Wc, const float* __restrict__ bc,
                            float* __restrict__ out, int n_graphs) {
    int g = blockIdx.x;
    int lo = 0, hi = N;
    while (lo < hi) { int mid = (lo + hi) >> 1; if (gid[mid] < g) lo = mid + 1; else hi = mid; }
    int start = lo;
    hi = N;
    while (lo < hi) { int mid = (lo + hi) >> 1; if (gid[mid] < g + 1) lo = mid + 1; else hi = mid; }
    int end = lo;
    int cnt = end - start;

    int lane = threadIdx.x & 63;
    int grp = threadIdx.x >> 6;
    float acc = 0.0f;
    for (int n = start + grp; n < end; n += 4) acc += h[(size_t)n * 64 + lane];

    __shared__ float sh[4][64];
    __shared__ float hrow[64];
    sh[grp][lane] = acc;
    __syncthreads();
    if (threadIdx.x < 64) {
        float s = sh[0][lane] + sh[1][lane] + sh[2][lane] + sh[3][lane];
        float m = s / fmaxf((float)cnt, 1.0f);
        hrow[lane] = m;
        out[(size_t)g * 64 + lane] = m;
    }
    __syncthreads();
    if (threadIdx.x < 10) {
        int c = threadIdx.x;
        float acc2 = bc[c];
        #pragma unroll
        for (int j = 0; j < 64; ++j) acc2 = fmaf(hrow[j], Wc[j * 10 + c], acc2);
        out[(size_t)n_graphs * 64 + (size_t)g * 10 + c] = acc2;
    }
}

extern "C" void kernel_launch(void* const* d_in, const int* in_sizes, int n_in,
                              void* d_out, int out_size, void* d_ws, size_t ws_size,
                              hipStream_t stream) {
    const int*   src = (const int*)d_in[0];
    const int*   dst = (const int*)d_in[1];
    const int*   gid = (const int*)d_in[2];
    const float* W1  = (const float*)d_in[4];
    const float* b1  = (const float*)d_in[5];
    const float* W2  = (const float*)d_in[6];
    const float* b2  = (const float*)d_in[7];
    const float* W3  = (const float*)d_in[8];
    const float* b3  = (const float*)d_in[9];
    const float* W4  = (const float*)d_in[10];
    const float* b4  = (const float*)d_in[11];
    const float* Wc  = (const float*)d_in[12];
    const float* bc  = (const float*)d_in[13];

    int E  = in_sizes[0];
    int N  = in_sizes[2];
    int ng = out_size / 74;

    // workspace carve-up (all 4-byte elements)
    int* in_deg_i   = (int*)d_ws;              // N
    int* out_deg_i  = in_deg_i + N;            // N
    int* row_ptr    = out_deg_i + N;           // N+1
    int* cursor     = row_ptr + N + 1;         // N
    int* csr_src    = cursor + N;              // E
    int* block_sums = csr_src + E;             // 1024
    int* block_offs = block_sums + 1024;       // 1024
    float* norm_src = (float*)(block_offs + 1024); // N
    float* norm_dst = norm_src + N;            // N
    float* xs       = norm_dst + N;            // N
    float* a_buf    = xs + N;                  // N
    float* bufA     = a_buf + N;               // 64N
    float* bufB     = bufA + 64 * (size_t)N;   // 64N

    float* out_f = (float*)d_out;

    int NB = (N + 1023) / 1024;

    // degrees (int atomics) + norms
    hipMemsetAsync(in_deg_i, 0, 2 * (size_t)N * sizeof(int), stream);
    deg_kernel<<<2048, 256, 0, stream>>>(src, dst, in_deg_i, out_deg_i, E);
    norm_kernel<<<(N + 255) / 256, 256, 0, stream>>>(in_deg_i, out_deg_i, norm_src, norm_dst, xs, N);

    // CSR by dst: prefix scan of in_deg, then cursor fill
    scan_reduce<<<NB, 256, 0, stream>>>(in_deg_i, block_sums, N);
    scan_top<<<1, 1024, 0, stream>>>(block_sums, block_offs, NB, row_ptr, N);
    scan_apply<<<NB, 256, 0, stream>>>(in_deg_i, block_offs, row_ptr, cursor, N);
    fill_kernel<<<2048, 256, 0, stream>>>(src, dst, cursor, csr_src, E);

    // layer 1 (scalar feature path)
    agg1_kernel<<<(N + 255) / 256, 256, 0, stream>>>(row_ptr, csr_src, xs, norm_dst, a_buf, N);
    dense1_kernel<<<2048, 256, 0, stream>>>(a_buf, norm_src, W1, b1, bufA, N);

    // layers 2-4: fused pull-aggregate + GEMV (+relu, +norm_src except last)
    conv_fused<<<2048, 256, 0, stream>>>(row_ptr, csr_src, bufA, norm_dst, norm_src, W2, b2, bufB, N, 1);
    conv_fused<<<2048, 256, 0, stream>>>(row_ptr, csr_src, bufB, norm_dst, norm_src, W3, b3, bufA, N, 1);
    conv_fused<<<2048, 256, 0, stream>>>(row_ptr, csr_src, bufA, norm_dst, norm_src, W4, b4, bufB, N, 0);

    // mean-pool + head
    pool_kernel<<<ng, 256, 0, stream>>>(bufB, gid, N, Wc, bc, out_f, ng);
}

// Round 5
// 939.824 us; speedup vs baseline: 1.8254x; 1.2230x over previous
//
#include <hip/hip_runtime.h>

// GCN classifier: CSR pull-based aggregation + fused GEMV per layer.
// Round 4 (resubmit): conv_fused uses float4 gathers with 4 edge-slots per
// wave (lane = 16*slot + feature_quad) for 8x memory-level parallelism.

// ---------- degree histogram (int atomics, once) ----------
__global__ void deg_kernel(const int* __restrict__ src, const int* __restrict__ dst,
                           int* __restrict__ in_deg, int* __restrict__ out_deg, int E) {
    int stride = gridDim.x * blockDim.x;
    int E4 = E >> 2;
    const int4* src4 = (const int4*)src;
    const int4* dst4 = (const int4*)dst;
    for (int e = blockIdx.x * blockDim.x + threadIdx.x; e < E4; e += stride) {
        int4 s = src4[e], d = dst4[e];
        atomicAdd(&in_deg[d.x], 1); atomicAdd(&in_deg[d.y], 1);
        atomicAdd(&in_deg[d.z], 1); atomicAdd(&in_deg[d.w], 1);
        atomicAdd(&out_deg[s.x], 1); atomicAdd(&out_deg[s.y], 1);
        atomicAdd(&out_deg[s.z], 1); atomicAdd(&out_deg[s.w], 1);
    }
    // tail
    int tid = blockIdx.x * blockDim.x + threadIdx.x;
    if (tid < (E & 3)) {
        int e = (E4 << 2) + tid;
        atomicAdd(&in_deg[dst[e]], 1);
        atomicAdd(&out_deg[src[e]], 1);
    }
}

// norms + layer-1 pre-scaled feature xs = in_deg * norm_src
__global__ void norm_kernel(const int* __restrict__ in_deg, const int* __restrict__ out_deg,
                            float* __restrict__ norm_src, float* __restrict__ norm_dst,
                            float* __restrict__ xs, int N) {
    int n = blockIdx.x * blockDim.x + threadIdx.x;
    if (n < N) {
        float id = (float)in_deg[n];
        float od = (float)out_deg[n];
        float ns = rsqrtf(fmaxf(od, 1.0f));
        norm_src[n] = ns;
        norm_dst[n] = rsqrtf(fmaxf(id, 1.0f));
        xs[n] = id * ns;
    }
}

// ---------- 3-kernel exclusive prefix scan of in_deg -> row_ptr ----------
__global__ void scan_reduce(const int* __restrict__ vals, int* __restrict__ block_sums, int N) {
    int t = threadIdx.x, b = blockIdx.x;
    int base = b * 1024 + t * 4;
    int s = 0;
    #pragma unroll
    for (int k = 0; k < 4; ++k) { int i = base + k; if (i < N) s += vals[i]; }
    for (int d = 32; d > 0; d >>= 1) s += __shfl_down(s, d, 64);
    __shared__ int wsum[4];
    if ((t & 63) == 0) wsum[t >> 6] = s;
    __syncthreads();
    if (t == 0) block_sums[b] = wsum[0] + wsum[1] + wsum[2] + wsum[3];
}

__global__ void scan_top(const int* __restrict__ block_sums, int* __restrict__ block_offs,
                         int NB, int* __restrict__ row_ptr, int N) {
    __shared__ int ts[1024];
    int t = threadIdx.x;
    int s = (t < NB) ? block_sums[t] : 0;
    ts[t] = s;
    __syncthreads();
    for (int d = 1; d < 1024; d <<= 1) {
        int x = (t >= d) ? ts[t - d] : 0;
        __syncthreads();
        ts[t] += x;
        __syncthreads();
    }
    block_offs[t] = ts[t] - s;
    if (t == 1023) row_ptr[N] = ts[1023];
}

__global__ void scan_apply(const int* __restrict__ vals, const int* __restrict__ block_offs,
                           int* __restrict__ row_ptr, int* __restrict__ cursor, int N) {
    __shared__ int ts[256];
    int t = threadIdx.x, b = blockIdx.x;
    int base = b * 1024 + t * 4;
    int v[4]; int s = 0;
    #pragma unroll
    for (int k = 0; k < 4; ++k) { int i = base + k; v[k] = (i < N) ? vals[i] : 0; s += v[k]; }
    ts[t] = s;
    __syncthreads();
    for (int d = 1; d < 256; d <<= 1) {
        int x = (t >= d) ? ts[t - d] : 0;
        __syncthreads();
        ts[t] += x;
        __syncthreads();
    }
    int ex = block_offs[b] + ts[t] - s;
    #pragma unroll
    for (int k = 0; k < 4; ++k) {
        int i = base + k;
        if (i < N) { row_ptr[i] = ex; cursor[i] = ex; }
        ex += v[k];
    }
}

// scatter edges into CSR rows via per-row atomic cursor
__global__ void fill_kernel(const int* __restrict__ src, const int* __restrict__ dst,
                            int* __restrict__ cursor, int* __restrict__ csr_src, int E) {
    int stride = gridDim.x * blockDim.x;
    int E4 = E >> 2;
    const int4* src4 = (const int4*)src;
    const int4* dst4 = (const int4*)dst;
    for (int e = blockIdx.x * blockDim.x + threadIdx.x; e < E4; e += stride) {
        int4 s = src4[e], d = dst4[e];
        csr_src[atomicAdd(&cursor[d.x], 1)] = s.x;
        csr_src[atomicAdd(&cursor[d.y], 1)] = s.y;
        csr_src[atomicAdd(&cursor[d.z], 1)] = s.z;
        csr_src[atomicAdd(&cursor[d.w], 1)] = s.w;
    }
    int tid = blockIdx.x * blockDim.x + threadIdx.x;
    if (tid < (E & 3)) {
        int e = (E4 << 2) + tid;
        csr_src[atomicAdd(&cursor[dst[e]], 1)] = src[e];
    }
}

// ---------- layer 1 (scalar feature) ----------
__global__ void agg1_kernel(const int* __restrict__ row_ptr, const int* __restrict__ csr_src,
                            const float* __restrict__ xs, const float* __restrict__ norm_dst,
                            float* __restrict__ a_buf, int N) {
    int n = blockIdx.x * blockDim.x + threadIdx.x;
    if (n < N) {
        int s0 = row_ptr[n], s1 = row_ptr[n + 1];
        float a = 0.0f;
        for (int i = s0; i < s1; ++i) a += xs[csr_src[i]];
        a_buf[n] = a * norm_dst[n];
    }
}

__global__ void dense1_kernel(const float* __restrict__ a_buf, const float* __restrict__ norm_src,
                              const float* __restrict__ W1, const float* __restrict__ b1,
                              float* __restrict__ out, int N) {
    int stride = gridDim.x * blockDim.x;
    int total = N * 64;
    for (int i = blockIdx.x * blockDim.x + threadIdx.x; i < total; i += stride) {
        int n = i >> 6, j = i & 63;
        float y = fmaxf(fmaf(a_buf[n], W1[j], b1[j]), 0.0f);
        out[i] = y * norm_src[n];
    }
}

// ---------- fused pull-aggregate + GEMV + relu + norm ----------
// One wave per node. lane = 16*slot + q: slot (0..3) = edge slot, q (0..15) =
// feature quad (features 4q..4q+3 as float4). Per inner iteration the wave has
// 4 independent 16B gathers in flight (4 edges x 256B rows).
__global__ void conv_fused(const int* __restrict__ row_ptr, const int* __restrict__ csr_src,
                           const float4* __restrict__ x4, const float* __restrict__ norm_dst,
                           const float* __restrict__ norm_src, const float* __restrict__ W,
                           const float* __restrict__ b, float* __restrict__ out,
                           int N, int apply_src) {
    __shared__ float Wsh[64 * 64];
    for (int i = threadIdx.x; i < 64 * 64; i += blockDim.x) Wsh[i] = W[i];
    __syncthreads();
    int lane = threadIdx.x & 63;
    int slot = lane >> 4;          // 0..3
    int q    = lane & 15;          // feature quad
    int grp  = threadIdx.x >> 6;
    int gpb  = blockDim.x >> 6;
    int gw   = blockIdx.x * gpb + grp;
    int nw   = gridDim.x * gpb;
    float bj = b[lane];
    for (int n = gw; n < N; n += nw) {
        int s0 = row_ptr[n], s1 = row_ptr[n + 1];
        float4 acc = make_float4(0.f, 0.f, 0.f, 0.f);
        for (int i = s0 + slot; i < s1; i += 4) {
            int s = csr_src[i];                       // broadcast within 16-lane group
            float4 v = x4[(size_t)s * 16 + q];        // 16 lanes x 16B = one 256B row
            acc.x += v.x; acc.y += v.y; acc.z += v.z; acc.w += v.w;
        }
        // reduce across the 4 edge slots (lanes with equal q)
        acc.x += __shfl_xor(acc.x, 16, 64); acc.y += __shfl_xor(acc.y, 16, 64);
        acc.z += __shfl_xor(acc.z, 16, 64); acc.w += __shfl_xor(acc.w, 16, 64);
        acc.x += __shfl_xor(acc.x, 32, 64); acc.y += __shfl_xor(acc.y, 32, 64);
        acc.z += __shfl_xor(acc.z, 32, 64); acc.w += __shfl_xor(acc.w, 32, 64);
        float nd = norm_dst[n];
        acc.x *= nd; acc.y *= nd; acc.z *= nd; acc.w *= nd;
        // GEMV: feature k lives in lane k>>2, component k&3
        float y = bj;
        #pragma unroll
        for (int k = 0; k < 64; ++k) {
            float comp = (k & 3) == 0 ? acc.x : (k & 3) == 1 ? acc.y : (k & 3) == 2 ? acc.z : acc.w;
            float vk = __shfl(comp, k >> 2, 64);
            y = fmaf(vk, Wsh[k * 64 + lane], y);
        }
        y = fmaxf(y, 0.0f);
        if (apply_src) y *= norm_src[n];
        out[(size_t)n * 64 + lane] = y;
    }
}

// ---------- mean-pool + classifier head (one block per graph) ----------
__global__ void pool_kernel(const float* __restrict__ h, const int* __restrict__ gid, int N,
                            const float* __restrict__ Wc, const float* __restrict__ bc,
                            float* __restrict__ out, int n_graphs) {
    int g = blockIdx.x;
    int lo = 0, hi = N;
    while (lo < hi) { int mid = (lo + hi) >> 1; if (gid[mid] < g) lo = mid + 1; else hi = mid; }
    int start = lo;
    hi = N;
    while (lo < hi) { int mid = (lo + hi) >> 1; if (gid[mid] < g + 1) lo = mid + 1; else hi = mid; }
    int end = lo;
    int cnt = end - start;

    int lane = threadIdx.x & 63;
    int grp = threadIdx.x >> 6;
    float acc = 0.0f;
    for (int n = start + grp; n < end; n += 4) acc += h[(size_t)n * 64 + lane];

    __shared__ float sh[4][64];
    __shared__ float hrow[64];
    sh[grp][lane] = acc;
    __syncthreads();
    if (threadIdx.x < 64) {
        float s = sh[0][lane] + sh[1][lane] + sh[2][lane] + sh[3][lane];
        float m = s / fmaxf((float)cnt, 1.0f);
        hrow[lane] = m;
        out[(size_t)g * 64 + lane] = m;
    }
    __syncthreads();
    if (threadIdx.x < 10) {
        int c = threadIdx.x;
        float acc2 = bc[c];
        #pragma unroll
        for (int j = 0; j < 64; ++j) acc2 = fmaf(hrow[j], Wc[j * 10 + c], acc2);
        out[(size_t)n_graphs * 64 + (size_t)g * 10 + c] = acc2;
    }
}

extern "C" void kernel_launch(void* const* d_in, const int* in_sizes, int n_in,
                              void* d_out, int out_size, void* d_ws, size_t ws_size,
                              hipStream_t stream) {
    const int*   src = (const int*)d_in[0];
    const int*   dst = (const int*)d_in[1];
    const int*   gid = (const int*)d_in[2];
    const float* W1  = (const float*)d_in[4];
    const float* b1  = (const float*)d_in[5];
    const float* W2  = (const float*)d_in[6];
    const float* b2  = (const float*)d_in[7];
    const float* W3  = (const float*)d_in[8];
    const float* b3  = (const float*)d_in[9];
    const float* W4  = (const float*)d_in[10];
    const float* b4  = (const float*)d_in[11];
    const float* Wc  = (const float*)d_in[12];
    const float* bc  = (const float*)d_in[13];

    int E  = in_sizes[0];
    int N  = in_sizes[2];
    int ng = out_size / 74;

    // workspace carve-up (4-byte elements); bufA aligned to 16B for float4
    int* in_deg_i   = (int*)d_ws;              // N
    int* out_deg_i  = in_deg_i + N;            // N
    int* row_ptr    = out_deg_i + N;           // N+1
    int* cursor     = row_ptr + N + 1;         // N
    int* csr_src    = cursor + N;              // E
    int* block_sums = csr_src + E;             // 1024
    int* block_offs = block_sums + 1024;       // 1024
    float* norm_src = (float*)(block_offs + 1024); // N
    float* norm_dst = norm_src + N;            // N
    float* xs       = norm_dst + N;            // N
    float* a_buf    = xs + N;                  // N
    float* bufA     = (float*)(((uintptr_t)(a_buf + N) + 15) & ~(uintptr_t)15); // 64N
    float* bufB     = bufA + 64 * (size_t)N;   // 64N

    float* out_f = (float*)d_out;

    int NB = (N + 1023) / 1024;

    hipMemsetAsync(in_deg_i, 0, 2 * (size_t)N * sizeof(int), stream);
    deg_kernel<<<2048, 256, 0, stream>>>(src, dst, in_deg_i, out_deg_i, E);
    norm_kernel<<<(N + 255) / 256, 256, 0, stream>>>(in_deg_i, out_deg_i, norm_src, norm_dst, xs, N);

    scan_reduce<<<NB, 256, 0, stream>>>(in_deg_i, block_sums, N);
    scan_top<<<1, 1024, 0, stream>>>(block_sums, block_offs, NB, row_ptr, N);
    scan_apply<<<NB, 256, 0, stream>>>(in_deg_i, block_offs, row_ptr, cursor, N);
    fill_kernel<<<2048, 256, 0, stream>>>(src, dst, cursor, csr_src, E);

    agg1_kernel<<<(N + 255) / 256, 256, 0, stream>>>(row_ptr, csr_src, xs, norm_dst, a_buf, N);
    dense1_kernel<<<2048, 256, 0, stream>>>(a_buf, norm_src, W1, b1, bufA, N);

    conv_fused<<<2048, 256, 0, stream>>>(row_ptr, csr_src, (const float4*)bufA, norm_dst, norm_src, W2, b2, bufB, N, 1);
    conv_fused<<<2048, 256, 0, stream>>>(row_ptr, csr_src, (const float4*)bufB, norm_dst, norm_src, W3, b3, bufA, N, 1);
    conv_fused<<<2048, 256, 0, stream>>>(row_ptr, csr_src, (const float4*)bufA, norm_dst, norm_src, W4, b4, bufB, N, 0);

    pool_kernel<<<ng, 256, 0, stream>>>(bufB, gid, N, Wc, bc, out_f, ng);
}

// Round 6
// 819.234 us; speedup vs baseline: 2.0941x; 1.1472x over previous
//
#include <hip/hip_runtime.h>

// GCN classifier: CSR pull-based aggregation + fused GEMV per layer.
// Round 6: conv_fused gather uses 8 edge-slots x 8 lanes, 2 x float4 per
// lane per edge -> 16 independent 16B loads in flight per iteration.

// ---------- degree histogram (int atomics, once) ----------
__global__ void deg_kernel(const int* __restrict__ src, const int* __restrict__ dst,
                           int* __restrict__ in_deg, int* __restrict__ out_deg, int E) {
    int stride = gridDim.x * blockDim.x;
    int E4 = E >> 2;
    const int4* src4 = (const int4*)src;
    const int4* dst4 = (const int4*)dst;
    for (int e = blockIdx.x * blockDim.x + threadIdx.x; e < E4; e += stride) {
        int4 s = src4[e], d = dst4[e];
        atomicAdd(&in_deg[d.x], 1); atomicAdd(&in_deg[d.y], 1);
        atomicAdd(&in_deg[d.z], 1); atomicAdd(&in_deg[d.w], 1);
        atomicAdd(&out_deg[s.x], 1); atomicAdd(&out_deg[s.y], 1);
        atomicAdd(&out_deg[s.z], 1); atomicAdd(&out_deg[s.w], 1);
    }
    int tid = blockIdx.x * blockDim.x + threadIdx.x;
    if (tid < (E & 3)) {
        int e = (E4 << 2) + tid;
        atomicAdd(&in_deg[dst[e]], 1);
        atomicAdd(&out_deg[src[e]], 1);
    }
}

// norms + layer-1 pre-scaled feature xs = in_deg * norm_src
__global__ void norm_kernel(const int* __restrict__ in_deg, const int* __restrict__ out_deg,
                            float* __restrict__ norm_src, float* __restrict__ norm_dst,
                            float* __restrict__ xs, int N) {
    int n = blockIdx.x * blockDim.x + threadIdx.x;
    if (n < N) {
        float id = (float)in_deg[n];
        float od = (float)out_deg[n];
        float ns = rsqrtf(fmaxf(od, 1.0f));
        norm_src[n] = ns;
        norm_dst[n] = rsqrtf(fmaxf(id, 1.0f));
        xs[n] = id * ns;
    }
}

// ---------- 3-kernel exclusive prefix scan of in_deg -> row_ptr ----------
__global__ void scan_reduce(const int* __restrict__ vals, int* __restrict__ block_sums, int N) {
    int t = threadIdx.x, b = blockIdx.x;
    int base = b * 1024 + t * 4;
    int s = 0;
    #pragma unroll
    for (int k = 0; k < 4; ++k) { int i = base + k; if (i < N) s += vals[i]; }
    for (int d = 32; d > 0; d >>= 1) s += __shfl_down(s, d, 64);
    __shared__ int wsum[4];
    if ((t & 63) == 0) wsum[t >> 6] = s;
    __syncthreads();
    if (t == 0) block_sums[b] = wsum[0] + wsum[1] + wsum[2] + wsum[3];
}

__global__ void scan_top(const int* __restrict__ block_sums, int* __restrict__ block_offs,
                         int NB, int* __restrict__ row_ptr, int N) {
    __shared__ int ts[1024];
    int t = threadIdx.x;
    int s = (t < NB) ? block_sums[t] : 0;
    ts[t] = s;
    __syncthreads();
    for (int d = 1; d < 1024; d <<= 1) {
        int x = (t >= d) ? ts[t - d] : 0;
        __syncthreads();
        ts[t] += x;
        __syncthreads();
    }
    block_offs[t] = ts[t] - s;
    if (t == 1023) row_ptr[N] = ts[1023];
}

__global__ void scan_apply(const int* __restrict__ vals, const int* __restrict__ block_offs,
                           int* __restrict__ row_ptr, int* __restrict__ cursor, int N) {
    __shared__ int ts[256];
    int t = threadIdx.x, b = blockIdx.x;
    int base = b * 1024 + t * 4;
    int v[4]; int s = 0;
    #pragma unroll
    for (int k = 0; k < 4; ++k) { int i = base + k; v[k] = (i < N) ? vals[i] : 0; s += v[k]; }
    ts[t] = s;
    __syncthreads();
    for (int d = 1; d < 256; d <<= 1) {
        int x = (t >= d) ? ts[t - d] : 0;
        __syncthreads();
        ts[t] += x;
        __syncthreads();
    }
    int ex = block_offs[b] + ts[t] - s;
    #pragma unroll
    for (int k = 0; k < 4; ++k) {
        int i = base + k;
        if (i < N) { row_ptr[i] = ex; cursor[i] = ex; }
        ex += v[k];
    }
}

// scatter edges into CSR rows via per-row atomic cursor
__global__ void fill_kernel(const int* __restrict__ src, const int* __restrict__ dst,
                            int* __restrict__ cursor, int* __restrict__ csr_src, int E) {
    int stride = gridDim.x * blockDim.x;
    int E4 = E >> 2;
    const int4* src4 = (const int4*)src;
    const int4* dst4 = (const int4*)dst;
    for (int e = blockIdx.x * blockDim.x + threadIdx.x; e < E4; e += stride) {
        int4 s = src4[e], d = dst4[e];
        csr_src[atomicAdd(&cursor[d.x], 1)] = s.x;
        csr_src[atomicAdd(&cursor[d.y], 1)] = s.y;
        csr_src[atomicAdd(&cursor[d.z], 1)] = s.z;
        csr_src[atomicAdd(&cursor[d.w], 1)] = s.w;
    }
    int tid = blockIdx.x * blockDim.x + threadIdx.x;
    if (tid < (E & 3)) {
        int e = (E4 << 2) + tid;
        csr_src[atomicAdd(&cursor[dst[e]], 1)] = src[e];
    }
}

// ---------- layer 1 (scalar feature) ----------
__global__ void agg1_kernel(const int* __restrict__ row_ptr, const int* __restrict__ csr_src,
                            const float* __restrict__ xs, const float* __restrict__ norm_dst,
                            float* __restrict__ a_buf, int N) {
    int n = blockIdx.x * blockDim.x + threadIdx.x;
    if (n < N) {
        int s0 = row_ptr[n], s1 = row_ptr[n + 1];
        float a = 0.0f;
        for (int i = s0; i < s1; ++i) a += xs[csr_src[i]];
        a_buf[n] = a * norm_dst[n];
    }
}

__global__ void dense1_kernel(const float* __restrict__ a_buf, const float* __restrict__ norm_src,
                              const float* __restrict__ W1, const float* __restrict__ b1,
                              float* __restrict__ out, int N) {
    int stride = gridDim.x * blockDim.x;
    int total = N * 64;
    for (int i = blockIdx.x * blockDim.x + threadIdx.x; i < total; i += stride) {
        int n = i >> 6, j = i & 63;
        float y = fmaxf(fmaf(a_buf[n], W1[j], b1[j]), 0.0f);
        out[i] = y * norm_src[n];
    }
}

// ---------- fused pull-aggregate + GEMV + relu + norm ----------
// One wave per node. lane = 8*slot + o: slot (0..7) = edge slot, o (0..7) =
// octant. Per edge, lane loads float4s at quads o and o+8 (bytes 16*o and
// 128+16*o) -> 8 lanes cover the 256B row; 8 edges in flight -> 16
// independent 16B loads per wave per iteration.
__global__ void conv_fused(const int* __restrict__ row_ptr, const int* __restrict__ csr_src,
                           const float4* __restrict__ x4, const float* __restrict__ norm_dst,
                           const float* __restrict__ norm_src, const float* __restrict__ W,
                           const float* __restrict__ b, float* __restrict__ out,
                           int N, int apply_src) {
    __shared__ float Wsh[64 * 64];
    for (int i = threadIdx.x; i < 64 * 64; i += blockDim.x) Wsh[i] = W[i];
    __syncthreads();
    int lane = threadIdx.x & 63;
    int slot = lane >> 3;          // 0..7 edge slot
    int o    = lane & 7;           // feature octant (quads o and o+8)
    int grp  = threadIdx.x >> 6;
    int gpb  = blockDim.x >> 6;
    int gw   = blockIdx.x * gpb + grp;
    int nw   = gridDim.x * gpb;
    float bj = b[lane];
    for (int n = gw; n < N; n += nw) {
        int s0 = row_ptr[n], s1 = row_ptr[n + 1];
        float4 accA = make_float4(0.f, 0.f, 0.f, 0.f);   // features 4o..4o+3
        float4 accB = make_float4(0.f, 0.f, 0.f, 0.f);   // features 32+4o..32+4o+3
        for (int i = s0 + slot; i < s1; i += 8) {
            int s = csr_src[i];                    // broadcast within 8-lane group
            float4 vA = x4[(size_t)s * 16 + o];
            float4 vB = x4[(size_t)s * 16 + 8 + o];
            accA.x += vA.x; accA.y += vA.y; accA.z += vA.z; accA.w += vA.w;
            accB.x += vB.x; accB.y += vB.y; accB.z += vB.z; accB.w += vB.w;
        }
        // reduce across the 8 edge slots (lanes with equal o): xor 8,16,32
        #pragma unroll
        for (int m = 8; m <= 32; m <<= 1) {
            accA.x += __shfl_xor(accA.x, m, 64); accA.y += __shfl_xor(accA.y, m, 64);
            accA.z += __shfl_xor(accA.z, m, 64); accA.w += __shfl_xor(accA.w, m, 64);
            accB.x += __shfl_xor(accB.x, m, 64); accB.y += __shfl_xor(accB.y, m, 64);
            accB.z += __shfl_xor(accB.z, m, 64); accB.w += __shfl_xor(accB.w, m, 64);
        }
        float nd = norm_dst[n];
        accA.x *= nd; accA.y *= nd; accA.z *= nd; accA.w *= nd;
        accB.x *= nd; accB.y *= nd; accB.z *= nd; accB.w *= nd;
        // GEMV: feature k (k<32) lives on lanes with o==k>>2, component k&3, accA;
        //       feature k>=32 on lanes with o==(k-32)>>2, accB.
        float y = bj;
        #pragma unroll
        for (int k = 0; k < 32; ++k) {
            float comp = (k & 3) == 0 ? accA.x : (k & 3) == 1 ? accA.y : (k & 3) == 2 ? accA.z : accA.w;
            float vk = __shfl(comp, k >> 2, 64);
            y = fmaf(vk, Wsh[k * 64 + lane], y);
        }
        #pragma unroll
        for (int k = 32; k < 64; ++k) {
            float comp = (k & 3) == 0 ? accB.x : (k & 3) == 1 ? accB.y : (k & 3) == 2 ? accB.z : accB.w;
            float vk = __shfl(comp, (k - 32) >> 2, 64);
            y = fmaf(vk, Wsh[k * 64 + lane], y);
        }
        y = fmaxf(y, 0.0f);
        if (apply_src) y *= norm_src[n];
        out[(size_t)n * 64 + lane] = y;
    }
}

// ---------- mean-pool + classifier head (one block per graph) ----------
__global__ void pool_kernel(const float* __restrict__ h, const int* __restrict__ gid, int N,
                            const float* __restrict__ Wc, const float* __restrict__ bc,
                            float* __restrict__ out, int n_graphs) {
    int g = blockIdx.x;
    int lo = 0, hi = N;
    while (lo < hi) { int mid = (lo + hi) >> 1; if (gid[mid] < g) lo = mid + 1; else hi = mid; }
    int start = lo;
    hi = N;
    while (lo < hi) { int mid = (lo + hi) >> 1; if (gid[mid] < g + 1) lo = mid + 1; else hi = mid; }
    int end = lo;
    int cnt = end - start;

    int lane = threadIdx.x & 63;
    int grp = threadIdx.x >> 6;
    float acc = 0.0f;
    for (int n = start + grp; n < end; n += 4) acc += h[(size_t)n * 64 + lane];

    __shared__ float sh[4][64];
    __shared__ float hrow[64];
    sh[grp][lane] = acc;
    __syncthreads();
    if (threadIdx.x < 64) {
        float s = sh[0][lane] + sh[1][lane] + sh[2][lane] + sh[3][lane];
        float m = s / fmaxf((float)cnt, 1.0f);
        hrow[lane] = m;
        out[(size_t)g * 64 + lane] = m;
    }
    __syncthreads();
    if (threadIdx.x < 10) {
        int c = threadIdx.x;
        float acc2 = bc[c];
        #pragma unroll
        for (int j = 0; j < 64; ++j) acc2 = fmaf(hrow[j], Wc[j * 10 + c], acc2);
        out[(size_t)n_graphs * 64 + (size_t)g * 10 + c] = acc2;
    }
}

extern "C" void kernel_launch(void* const* d_in, const int* in_sizes, int n_in,
                              void* d_out, int out_size, void* d_ws, size_t ws_size,
                              hipStream_t stream) {
    const int*   src = (const int*)d_in[0];
    const int*   dst = (const int*)d_in[1];
    const int*   gid = (const int*)d_in[2];
    const float* W1  = (const float*)d_in[4];
    const float* b1  = (const float*)d_in[5];
    const float* W2  = (const float*)d_in[6];
    const float* b2  = (const float*)d_in[7];
    const float* W3  = (const float*)d_in[8];
    const float* b3  = (const float*)d_in[9];
    const float* W4  = (const float*)d_in[10];
    const float* b4  = (const float*)d_in[11];
    const float* Wc  = (const float*)d_in[12];
    const float* bc  = (const float*)d_in[13];

    int E  = in_sizes[0];
    int N  = in_sizes[2];
    int ng = out_size / 74;

    // workspace carve-up (4-byte elements); bufA aligned to 16B for float4
    int* in_deg_i   = (int*)d_ws;              // N
    int* out_deg_i  = in_deg_i + N;            // N
    int* row_ptr    = out_deg_i + N;           // N+1
    int* cursor     = row_ptr + N + 1;         // N
    int* csr_src    = cursor + N;              // E
    int* block_sums = csr_src + E;             // 1024
    int* block_offs = block_sums + 1024;       // 1024
    float* norm_src = (float*)(block_offs + 1024); // N
    float* norm_dst = norm_src + N;            // N
    float* xs       = norm_dst + N;            // N
    float* a_buf    = xs + N;                  // N
    float* bufA     = (float*)(((uintptr_t)(a_buf + N) + 15) & ~(uintptr_t)15); // 64N
    float* bufB     = bufA + 64 * (size_t)N;   // 64N

    float* out_f = (float*)d_out;

    int NB = (N + 1023) / 1024;

    hipMemsetAsync(in_deg_i, 0, 2 * (size_t)N * sizeof(int), stream);
    deg_kernel<<<2048, 256, 0, stream>>>(src, dst, in_deg_i, out_deg_i, E);
    norm_kernel<<<(N + 255) / 256, 256, 0, stream>>>(in_deg_i, out_deg_i, norm_src, norm_dst, xs, N);

    scan_reduce<<<NB, 256, 0, stream>>>(in_deg_i, block_sums, N);
    scan_top<<<1, 1024, 0, stream>>>(block_sums, block_offs, NB, row_ptr, N);
    scan_apply<<<NB, 256, 0, stream>>>(in_deg_i, block_offs, row_ptr, cursor, N);
    fill_kernel<<<2048, 256, 0, stream>>>(src, dst, cursor, csr_src, E);

    agg1_kernel<<<(N + 255) / 256, 256, 0, stream>>>(row_ptr, csr_src, xs, norm_dst, a_buf, N);
    dense1_kernel<<<2048, 256, 0, stream>>>(a_buf, norm_src, W1, b1, bufA, N);

    conv_fused<<<2048, 256, 0, stream>>>(row_ptr, csr_src, (const float4*)bufA, norm_dst, norm_src, W2, b2, bufB, N, 1);
    conv_fused<<<2048, 256, 0, stream>>>(row_ptr, csr_src, (const float4*)bufB, norm_dst, norm_src, W3, b3, bufA, N, 1);
    conv_fused<<<2048, 256, 0, stream>>>(row_ptr, csr_src, (const float4*)bufA, norm_dst, norm_src, W4, b4, bufB, N, 0);

    pool_kernel<<<ng, 256, 0, stream>>>(bufB, gid, N, Wc, bc, out_f, ng);
}

// Round 8
// 780.558 us; speedup vs baseline: 2.1979x; 1.0495x over previous
//
#include <hip/hip_runtime.h>

// GCN classifier: CSR pull-based aggregation + fused GEMV per layer.
// Round 7 (resubmit): fill_kernel is XCD-sliced — blockIdx&7 picks a dst-range
// slice so all stores to a csr_src line come from one XCD's L2 and merge
// before writeback (round 6: 108 MB HBM write traffic for a 6.4 MB payload).

// ---------- degree histogram (int atomics, once) ----------
__global__ void deg_kernel(const int* __restrict__ src, const int* __restrict__ dst,
                           int* __restrict__ in_deg, int* __restrict__ out_deg, int E) {
    int stride = gridDim.x * blockDim.x;
    int E4 = E >> 2;
    const int4* src4 = (const int4*)src;
    const int4* dst4 = (const int4*)dst;
    for (int e = blockIdx.x * blockDim.x + threadIdx.x; e < E4; e += stride) {
        int4 s = src4[e], d = dst4[e];
        atomicAdd(&in_deg[d.x], 1); atomicAdd(&in_deg[d.y], 1);
        atomicAdd(&in_deg[d.z], 1); atomicAdd(&in_deg[d.w], 1);
        atomicAdd(&out_deg[s.x], 1); atomicAdd(&out_deg[s.y], 1);
        atomicAdd(&out_deg[s.z], 1); atomicAdd(&out_deg[s.w], 1);
    }
    int tid = blockIdx.x * blockDim.x + threadIdx.x;
    if (tid < (E & 3)) {
        int e = (E4 << 2) + tid;
        atomicAdd(&in_deg[dst[e]], 1);
        atomicAdd(&out_deg[src[e]], 1);
    }
}

// norms + layer-1 pre-scaled feature xs = in_deg * norm_src
__global__ void norm_kernel(const int* __restrict__ in_deg, const int* __restrict__ out_deg,
                            float* __restrict__ norm_src, float* __restrict__ norm_dst,
                            float* __restrict__ xs, int N) {
    int n = blockIdx.x * blockDim.x + threadIdx.x;
    if (n < N) {
        float id = (float)in_deg[n];
        float od = (float)out_deg[n];
        float ns = rsqrtf(fmaxf(od, 1.0f));
        norm_src[n] = ns;
        norm_dst[n] = rsqrtf(fmaxf(id, 1.0f));
        xs[n] = id * ns;
    }
}

// ---------- 3-kernel exclusive prefix scan of in_deg -> row_ptr ----------
__global__ void scan_reduce(const int* __restrict__ vals, int* __restrict__ block_sums, int N) {
    int t = threadIdx.x, b = blockIdx.x;
    int base = b * 1024 + t * 4;
    int s = 0;
    #pragma unroll
    for (int k = 0; k < 4; ++k) { int i = base + k; if (i < N) s += vals[i]; }
    for (int d = 32; d > 0; d >>= 1) s += __shfl_down(s, d, 64);
    __shared__ int wsum[4];
    if ((t & 63) == 0) wsum[t >> 6] = s;
    __syncthreads();
    if (t == 0) block_sums[b] = wsum[0] + wsum[1] + wsum[2] + wsum[3];
}

__global__ void scan_top(const int* __restrict__ block_sums, int* __restrict__ block_offs,
                         int NB, int* __restrict__ row_ptr, int N) {
    __shared__ int ts[1024];
    int t = threadIdx.x;
    int s = (t < NB) ? block_sums[t] : 0;
    ts[t] = s;
    __syncthreads();
    for (int d = 1; d < 1024; d <<= 1) {
        int x = (t >= d) ? ts[t - d] : 0;
        __syncthreads();
        ts[t] += x;
        __syncthreads();
    }
    block_offs[t] = ts[t] - s;
    if (t == 1023) row_ptr[N] = ts[1023];
}

__global__ void scan_apply(const int* __restrict__ vals, const int* __restrict__ block_offs,
                           int* __restrict__ row_ptr, int* __restrict__ cursor, int N) {
    __shared__ int ts[256];
    int t = threadIdx.x, b = blockIdx.x;
    int base = b * 1024 + t * 4;
    int v[4]; int s = 0;
    #pragma unroll
    for (int k = 0; k < 4; ++k) { int i = base + k; v[k] = (i < N) ? vals[i] : 0; s += v[k]; }
    ts[t] = s;
    __syncthreads();
    for (int d = 1; d < 256; d <<= 1) {
        int x = (t >= d) ? ts[t - d] : 0;
        __syncthreads();
        ts[t] += x;
        __syncthreads();
    }
    int ex = block_offs[b] + ts[t] - s;
    #pragma unroll
    for (int k = 0; k < 4; ++k) {
        int i = base + k;
        if (i < N) { row_ptr[i] = ex; cursor[i] = ex; }
        ex += v[k];
    }
}

// XCD-sliced CSR fill: slice-group s (blockIdx&7) scans ALL edges, writes only
// those with dst in node-slice s. Edge-list re-reads are sequential and served
// by L3; csr_src lines now merge in a single XCD's L2 before writeback.
__global__ void fill_kernel(const int* __restrict__ src, const int* __restrict__ dst,
                            int* __restrict__ cursor, int* __restrict__ csr_src, int E, int N) {
    int slice = blockIdx.x & 7;
    int bs    = blockIdx.x >> 3;          // block index within slice group
    int nbs   = gridDim.x >> 3;           // blocks per slice group
    int lo = (int)(((long long)slice * N) / 8);
    int hi = (slice == 7) ? N : (int)(((long long)(slice + 1) * N) / 8);
    int stride = nbs * blockDim.x;
    int E4 = E >> 2;
    const int4* src4 = (const int4*)src;
    const int4* dst4 = (const int4*)dst;
    for (int e = bs * blockDim.x + threadIdx.x; e < E4; e += stride) {
        int4 s = src4[e], d = dst4[e];
        if (d.x >= lo && d.x < hi) csr_src[atomicAdd(&cursor[d.x], 1)] = s.x;
        if (d.y >= lo && d.y < hi) csr_src[atomicAdd(&cursor[d.y], 1)] = s.y;
        if (d.z >= lo && d.z < hi) csr_src[atomicAdd(&cursor[d.z], 1)] = s.z;
        if (d.w >= lo && d.w < hi) csr_src[atomicAdd(&cursor[d.w], 1)] = s.w;
    }
    // tail (<=3 edges): slice 0, block 0 handles them unfiltered
    if (slice == 0 && bs == 0) {
        int tid = threadIdx.x;
        if (tid < (E & 3)) {
            int e = (E4 << 2) + tid;
            csr_src[atomicAdd(&cursor[dst[e]], 1)] = src[e];
        }
    }
}

// ---------- layer 1 (scalar feature) ----------
__global__ void agg1_kernel(const int* __restrict__ row_ptr, const int* __restrict__ csr_src,
                            const float* __restrict__ xs, const float* __restrict__ norm_dst,
                            float* __restrict__ a_buf, int N) {
    int n = blockIdx.x * blockDim.x + threadIdx.x;
    if (n < N) {
        int s0 = row_ptr[n], s1 = row_ptr[n + 1];
        float a = 0.0f;
        for (int i = s0; i < s1; ++i) a += xs[csr_src[i]];
        a_buf[n] = a * norm_dst[n];
    }
}

__global__ void dense1_kernel(const float* __restrict__ a_buf, const float* __restrict__ norm_src,
                              const float* __restrict__ W1, const float* __restrict__ b1,
                              float* __restrict__ out, int N) {
    int stride = gridDim.x * blockDim.x;
    int total = N * 64;
    for (int i = blockIdx.x * blockDim.x + threadIdx.x; i < total; i += stride) {
        int n = i >> 6, j = i & 63;
        float y = fmaxf(fmaf(a_buf[n], W1[j], b1[j]), 0.0f);
        out[i] = y * norm_src[n];
    }
}

// ---------- fused pull-aggregate + GEMV + relu + norm ----------
// One wave per node. lane = 8*slot + o: slot (0..7) = edge slot, o (0..7) =
// octant. Per edge, lane loads float4s at quads o and o+8 -> 8 lanes cover the
// 256B row; 8 edges in flight -> 16 independent 16B loads per iteration.
__global__ void conv_fused(const int* __restrict__ row_ptr, const int* __restrict__ csr_src,
                           const float4* __restrict__ x4, const float* __restrict__ norm_dst,
                           const float* __restrict__ norm_src, const float* __restrict__ W,
                           const float* __restrict__ b, float* __restrict__ out,
                           int N, int apply_src) {
    __shared__ float Wsh[64 * 64];
    for (int i = threadIdx.x; i < 64 * 64; i += blockDim.x) Wsh[i] = W[i];
    __syncthreads();
    int lane = threadIdx.x & 63;
    int slot = lane >> 3;          // 0..7 edge slot
    int o    = lane & 7;           // feature octant (quads o and o+8)
    int grp  = threadIdx.x >> 6;
    int gpb  = blockDim.x >> 6;
    int gw   = blockIdx.x * gpb + grp;
    int nw   = gridDim.x * gpb;
    float bj = b[lane];
    for (int n = gw; n < N; n += nw) {
        int s0 = row_ptr[n], s1 = row_ptr[n + 1];
        float4 accA = make_float4(0.f, 0.f, 0.f, 0.f);   // features 4o..4o+3
        float4 accB = make_float4(0.f, 0.f, 0.f, 0.f);   // features 32+4o..32+4o+3
        for (int i = s0 + slot; i < s1; i += 8) {
            int s = csr_src[i];                    // broadcast within 8-lane group
            float4 vA = x4[(size_t)s * 16 + o];
            float4 vB = x4[(size_t)s * 16 + 8 + o];
            accA.x += vA.x; accA.y += vA.y; accA.z += vA.z; accA.w += vA.w;
            accB.x += vB.x; accB.y += vB.y; accB.z += vB.z; accB.w += vB.w;
        }
        // reduce across the 8 edge slots (lanes with equal o): xor 8,16,32
        #pragma unroll
        for (int m = 8; m <= 32; m <<= 1) {
            accA.x += __shfl_xor(accA.x, m, 64); accA.y += __shfl_xor(accA.y, m, 64);
            accA.z += __shfl_xor(accA.z, m, 64); accA.w += __shfl_xor(accA.w, m, 64);
            accB.x += __shfl_xor(accB.x, m, 64); accB.y += __shfl_xor(accB.y, m, 64);
            accB.z += __shfl_xor(accB.z, m, 64); accB.w += __shfl_xor(accB.w, m, 64);
        }
        float nd = norm_dst[n];
        accA.x *= nd; accA.y *= nd; accA.z *= nd; accA.w *= nd;
        accB.x *= nd; accB.y *= nd; accB.z *= nd; accB.w *= nd;
        // GEMV: feature k (k<32) lives on lanes with o==k>>2, component k&3, accA;
        //       feature k>=32 on lanes with o==(k-32)>>2, accB.
        float y = bj;
        #pragma unroll
        for (int k = 0; k < 32; ++k) {
            float comp = (k & 3) == 0 ? accA.x : (k & 3) == 1 ? accA.y : (k & 3) == 2 ? accA.z : accA.w;
            float vk = __shfl(comp, k >> 2, 64);
            y = fmaf(vk, Wsh[k * 64 + lane], y);
        }
        #pragma unroll
        for (int k = 32; k < 64; ++k) {
            float comp = (k & 3) == 0 ? accB.x : (k & 3) == 1 ? accB.y : (k & 3) == 2 ? accB.z : accB.w;
            float vk = __shfl(comp, (k - 32) >> 2, 64);
            y = fmaf(vk, Wsh[k * 64 + lane], y);
        }
        y = fmaxf(y, 0.0f);
        if (apply_src) y *= norm_src[n];
        out[(size_t)n * 64 + lane] = y;
    }
}

// ---------- mean-pool + classifier head (one block per graph) ----------
__global__ void pool_kernel(const float* __restrict__ h, const int* __restrict__ gid, int N,
                            const float* __restrict__ Wc, const float* __restrict__ bc,
                            float* __restrict__ out, int n_graphs) {
    int g = blockIdx.x;
    int lo = 0, hi = N;
    while (lo < hi) { int mid = (lo + hi) >> 1; if (gid[mid] < g) lo = mid + 1; else hi = mid; }
    int start = lo;
    hi = N;
    while (lo < hi) { int mid = (lo + hi) >> 1; if (gid[mid] < g + 1) lo = mid + 1; else hi = mid; }
    int end = lo;
    int cnt = end - start;

    int lane = threadIdx.x & 63;
    int grp = threadIdx.x >> 6;
    float acc = 0.0f;
    for (int n = start + grp; n < end; n += 4) acc += h[(size_t)n * 64 + lane];

    __shared__ float sh[4][64];
    __shared__ float hrow[64];
    sh[grp][lane] = acc;
    __syncthreads();
    if (threadIdx.x < 64) {
        float s = sh[0][lane] + sh[1][lane] + sh[2][lane] + sh[3][lane];
        float m = s / fmaxf((float)cnt, 1.0f);
        hrow[lane] = m;
        out[(size_t)g * 64 + lane] = m;
    }
    __syncthreads();
    if (threadIdx.x < 10) {
        int c = threadIdx.x;
        float acc2 = bc[c];
        #pragma unroll
        for (int j = 0; j < 64; ++j) acc2 = fmaf(hrow[j], Wc[j * 10 + c], acc2);
        out[(size_t)n_graphs * 64 + (size_t)g * 10 + c] = acc2;
    }
}

extern "C" void kernel_launch(void* const* d_in, const int* in_sizes, int n_in,
                              void* d_out, int out_size, void* d_ws, size_t ws_size,
                              hipStream_t stream) {
    const int*   src = (const int*)d_in[0];
    const int*   dst = (const int*)d_in[1];
    const int*   gid = (const int*)d_in[2];
    const float* W1  = (const float*)d_in[4];
    const float* b1  = (const float*)d_in[5];
    const float* W2  = (const float*)d_in[6];
    const float* b2  = (const float*)d_in[7];
    const float* W3  = (const float*)d_in[8];
    const float* b3  = (const float*)d_in[9];
    const float* W4  = (const float*)d_in[10];
    const float* b4  = (const float*)d_in[11];
    const float* Wc  = (const float*)d_in[12];
    const float* bc  = (const float*)d_in[13];

    int E  = in_sizes[0];
    int N  = in_sizes[2];
    int ng = out_size / 74;

    // workspace carve-up (4-byte elements); bufA aligned to 16B for float4
    int* in_deg_i   = (int*)d_ws;              // N
    int* out_deg_i  = in_deg_i + N;            // N
    int* row_ptr    = out_deg_i + N;           // N+1
    int* cursor     = row_ptr + N + 1;         // N
    int* csr_src    = cursor + N;              // E
    int* block_sums = csr_src + E;             // 1024
    int* block_offs = block_sums + 1024;       // 1024
    float* norm_src = (float*)(block_offs + 1024); // N
    float* norm_dst = norm_src + N;            // N
    float* xs       = norm_dst + N;            // N
    float* a_buf    = xs + N;                  // N
    float* bufA     = (float*)(((uintptr_t)(a_buf + N) + 15) & ~(uintptr_t)15); // 64N
    float* bufB     = bufA + 64 * (size_t)N;   // 64N

    float* out_f = (float*)d_out;

    int NB = (N + 1023) / 1024;

    hipMemsetAsync(in_deg_i, 0, 2 * (size_t)N * sizeof(int), stream);
    deg_kernel<<<2048, 256, 0, stream>>>(src, dst, in_deg_i, out_deg_i, E);
    norm_kernel<<<(N + 255) / 256, 256, 0, stream>>>(in_deg_i, out_deg_i, norm_src, norm_dst, xs, N);

    scan_reduce<<<NB, 256, 0, stream>>>(in_deg_i, block_sums, N);
    scan_top<<<1, 1024, 0, stream>>>(block_sums, block_offs, NB, row_ptr, N);
    scan_apply<<<NB, 256, 0, stream>>>(in_deg_i, block_offs, row_ptr, cursor, N);
    fill_kernel<<<2048, 256, 0, stream>>>(src, dst, cursor, csr_src, E, N);

    agg1_kernel<<<(N + 255) / 256, 256, 0, stream>>>(row_ptr, csr_src, xs, norm_dst, a_buf, N);
    dense1_kernel<<<2048, 256, 0, stream>>>(a_buf, norm_src, W1, b1, bufA, N);

    conv_fused<<<2048, 256, 0, stream>>>(row_ptr, csr_src, (const float4*)bufA, norm_dst, norm_src, W2, b2, bufB, N, 1);
    conv_fused<<<2048, 256, 0, stream>>>(row_ptr, csr_src, (const float4*)bufB, norm_dst, norm_src, W3, b3, bufA, N, 1);
    conv_fused<<<2048, 256, 0, stream>>>(row_ptr, csr_src, (const float4*)bufA, norm_dst, norm_src, W4, b4, bufB, N, 0);

    pool_kernel<<<ng, 256, 0, stream>>>(bufB, gid, N, Wc, bc, out_f, ng);
}

// Round 12
// 779.406 us; speedup vs baseline: 2.2012x; 1.0015x over previous
//
#include <hip/hip_runtime.h>
#include <hip/hip_bf16.h>

// GCN classifier: CSR pull-based aggregation + fused GEMV per layer.
// Round 12: (a) deg_kernel XCD-sliced (pending from R9: 99.8 MB HBM writes
// for two 400 KB histograms); (b) intermediate h buffers stored as bf16 —
// halves gather bytes AND L2-line requests per edge (round 6 showed the
// gather path throughput-limited). All math stays fp32; only h1/h2/h3
// storage is bf16. Layer-4 output + pooling remain fp32.

// ---------- XCD-sliced degree histogram ----------
__global__ void deg_kernel(const int* __restrict__ src, const int* __restrict__ dst,
                           int* __restrict__ in_deg, int* __restrict__ out_deg, int E, int N) {
    int slice = blockIdx.x & 7;
    int bs    = blockIdx.x >> 3;
    int nbs   = gridDim.x >> 3;
    int lo = (int)(((long long)slice * N) / 8);
    int hi = (slice == 7) ? N : (int)(((long long)(slice + 1) * N) / 8);
    int stride = nbs * blockDim.x;
    int E4 = E >> 2;
    const int4* src4 = (const int4*)src;
    const int4* dst4 = (const int4*)dst;
    for (int e = bs * blockDim.x + threadIdx.x; e < E4; e += stride) {
        int4 s = src4[e], d = dst4[e];
        if (d.x >= lo && d.x < hi) atomicAdd(&in_deg[d.x], 1);
        if (d.y >= lo && d.y < hi) atomicAdd(&in_deg[d.y], 1);
        if (d.z >= lo && d.z < hi) atomicAdd(&in_deg[d.z], 1);
        if (d.w >= lo && d.w < hi) atomicAdd(&in_deg[d.w], 1);
        if (s.x >= lo && s.x < hi) atomicAdd(&out_deg[s.x], 1);
        if (s.y >= lo && s.y < hi) atomicAdd(&out_deg[s.y], 1);
        if (s.z >= lo && s.z < hi) atomicAdd(&out_deg[s.z], 1);
        if (s.w >= lo && s.w < hi) atomicAdd(&out_deg[s.w], 1);
    }
    if (slice == 0 && bs == 0) {
        int tid = threadIdx.x;
        if (tid < (E & 3)) {
            int e = (E4 << 2) + tid;
            atomicAdd(&in_deg[dst[e]], 1);
            atomicAdd(&out_deg[src[e]], 1);
        }
    }
}

// norms + layer-1 pre-scaled feature xs = in_deg * norm_src
__global__ void norm_kernel(const int* __restrict__ in_deg, const int* __restrict__ out_deg,
                            float* __restrict__ norm_src, float* __restrict__ norm_dst,
                            float* __restrict__ xs, int N) {
    int n = blockIdx.x * blockDim.x + threadIdx.x;
    if (n < N) {
        float id = (float)in_deg[n];
        float od = (float)out_deg[n];
        float ns = rsqrtf(fmaxf(od, 1.0f));
        norm_src[n] = ns;
        norm_dst[n] = rsqrtf(fmaxf(id, 1.0f));
        xs[n] = id * ns;
    }
}

// ---------- 3-kernel exclusive prefix scan of in_deg -> row_ptr ----------
__global__ void scan_reduce(const int* __restrict__ vals, int* __restrict__ block_sums, int N) {
    int t = threadIdx.x, b = blockIdx.x;
    int base = b * 1024 + t * 4;
    int s = 0;
    #pragma unroll
    for (int k = 0; k < 4; ++k) { int i = base + k; if (i < N) s += vals[i]; }
    for (int d = 32; d > 0; d >>= 1) s += __shfl_down(s, d, 64);
    __shared__ int wsum[4];
    if ((t & 63) == 0) wsum[t >> 6] = s;
    __syncthreads();
    if (t == 0) block_sums[b] = wsum[0] + wsum[1] + wsum[2] + wsum[3];
}

__global__ void scan_top(const int* __restrict__ block_sums, int* __restrict__ block_offs,
                         int NB, int* __restrict__ row_ptr, int N) {
    __shared__ int ts[1024];
    int t = threadIdx.x;
    int s = (t < NB) ? block_sums[t] : 0;
    ts[t] = s;
    __syncthreads();
    for (int d = 1; d < 1024; d <<= 1) {
        int x = (t >= d) ? ts[t - d] : 0;
        __syncthreads();
        ts[t] += x;
        __syncthreads();
    }
    block_offs[t] = ts[t] - s;
    if (t == 1023) row_ptr[N] = ts[1023];
}

__global__ void scan_apply(const int* __restrict__ vals, const int* __restrict__ block_offs,
                           int* __restrict__ row_ptr, int* __restrict__ cursor, int N) {
    __shared__ int ts[256];
    int t = threadIdx.x, b = blockIdx.x;
    int base = b * 1024 + t * 4;
    int v[4]; int s = 0;
    #pragma unroll
    for (int k = 0; k < 4; ++k) { int i = base + k; v[k] = (i < N) ? vals[i] : 0; s += v[k]; }
    ts[t] = s;
    __syncthreads();
    for (int d = 1; d < 256; d <<= 1) {
        int x = (t >= d) ? ts[t - d] : 0;
        __syncthreads();
        ts[t] += x;
        __syncthreads();
    }
    int ex = block_offs[b] + ts[t] - s;
    #pragma unroll
    for (int k = 0; k < 4; ++k) {
        int i = base + k;
        if (i < N) { row_ptr[i] = ex; cursor[i] = ex; }
        ex += v[k];
    }
}

// XCD-sliced CSR fill
__global__ void fill_kernel(const int* __restrict__ src, const int* __restrict__ dst,
                            int* __restrict__ cursor, int* __restrict__ csr_src, int E, int N) {
    int slice = blockIdx.x & 7;
    int bs    = blockIdx.x >> 3;
    int nbs   = gridDim.x >> 3;
    int lo = (int)(((long long)slice * N) / 8);
    int hi = (slice == 7) ? N : (int)(((long long)(slice + 1) * N) / 8);
    int stride = nbs * blockDim.x;
    int E4 = E >> 2;
    const int4* src4 = (const int4*)src;
    const int4* dst4 = (const int4*)dst;
    for (int e = bs * blockDim.x + threadIdx.x; e < E4; e += stride) {
        int4 s = src4[e], d = dst4[e];
        if (d.x >= lo && d.x < hi) csr_src[atomicAdd(&cursor[d.x], 1)] = s.x;
        if (d.y >= lo && d.y < hi) csr_src[atomicAdd(&cursor[d.y], 1)] = s.y;
        if (d.z >= lo && d.z < hi) csr_src[atomicAdd(&cursor[d.z], 1)] = s.z;
        if (d.w >= lo && d.w < hi) csr_src[atomicAdd(&cursor[d.w], 1)] = s.w;
    }
    if (slice == 0 && bs == 0) {
        int tid = threadIdx.x;
        if (tid < (E & 3)) {
            int e = (E4 << 2) + tid;
            csr_src[atomicAdd(&cursor[dst[e]], 1)] = src[e];
        }
    }
}

// ---------- layer 1 (scalar feature) ----------
__global__ void agg1_kernel(const int* __restrict__ row_ptr, const int* __restrict__ csr_src,
                            const float* __restrict__ xs, const float* __restrict__ norm_dst,
                            float* __restrict__ a_buf, int N) {
    int n = blockIdx.x * blockDim.x + threadIdx.x;
    if (n < N) {
        int s0 = row_ptr[n], s1 = row_ptr[n + 1];
        float a = 0.0f;
        for (int i = s0; i < s1; ++i) a += xs[csr_src[i]];
        a_buf[n] = a * norm_dst[n];
    }
}

// layer-1 dense, output stored bf16 (feeds conv2's bf16 gather)
__global__ void dense1_kernel(const float* __restrict__ a_buf, const float* __restrict__ norm_src,
                              const float* __restrict__ W1, const float* __restrict__ b1,
                              __hip_bfloat16* __restrict__ out, int N) {
    int stride = gridDim.x * blockDim.x;
    int total = N * 64;
    for (int i = blockIdx.x * blockDim.x + threadIdx.x; i < total; i += stride) {
        int n = i >> 6, j = i & 63;
        float y = fmaxf(fmaf(a_buf[n], W1[j], b1[j]), 0.0f);
        out[i] = __float2bfloat16(y * norm_src[n]);
    }
}

// ---------- fused pull-aggregate (bf16 x) + GEMV + relu + norm ----------
// One wave per node. lane = 8*slot + q: slot (0..7) = edge slot, q (0..7) =
// uint4 index in the 128B bf16 row (features 8q..8q+7). One 16B load per lane
// per edge covers the whole row with 8 lanes; 8 edges in flight per iteration,
// half the bytes and L2-line requests of the fp32 version.
__global__ void conv_fused(const int* __restrict__ row_ptr, const int* __restrict__ csr_src,
                           const uint4* __restrict__ xb, const float* __restrict__ norm_dst,
                           const float* __restrict__ norm_src, const float* __restrict__ W,
                           const float* __restrict__ b, float* __restrict__ out_f32,
                           __hip_bfloat16* __restrict__ out_bf,
                           int N, int apply_src, int store_bf16) {
    __shared__ float Wsh[64 * 64];
    for (int i = threadIdx.x; i < 64 * 64; i += blockDim.x) Wsh[i] = W[i];
    __syncthreads();
    int lane = threadIdx.x & 63;
    int slot = lane >> 3;          // 0..7 edge slot
    int q    = lane & 7;           // uint4 index within row
    int grp  = threadIdx.x >> 6;
    int gpb  = blockDim.x >> 6;
    int gw   = blockIdx.x * gpb + grp;
    int nw   = gridDim.x * gpb;
    float bj = b[lane];
    for (int n = gw; n < N; n += nw) {
        int s0 = row_ptr[n], s1 = row_ptr[n + 1];
        float f0 = 0.f, f1 = 0.f, f2 = 0.f, f3 = 0.f,
              f4 = 0.f, f5 = 0.f, f6 = 0.f, f7 = 0.f;   // features 8q..8q+7
        for (int i = s0 + slot; i < s1; i += 8) {
            int s = csr_src[i];                     // broadcast within 8-lane group
            uint4 u = xb[(size_t)s * 8 + q];        // 16B = 8 bf16
            f0 += __uint_as_float(u.x << 16);
            f1 += __uint_as_float(u.x & 0xFFFF0000u);
            f2 += __uint_as_float(u.y << 16);
            f3 += __uint_as_float(u.y & 0xFFFF0000u);
            f4 += __uint_as_float(u.z << 16);
            f5 += __uint_as_float(u.z & 0xFFFF0000u);
            f6 += __uint_as_float(u.w << 16);
            f7 += __uint_as_float(u.w & 0xFFFF0000u);
        }
        // reduce across the 8 edge slots (lanes with equal q): xor 8,16,32
        #pragma unroll
        for (int m = 8; m <= 32; m <<= 1) {
            f0 += __shfl_xor(f0, m, 64); f1 += __shfl_xor(f1, m, 64);
            f2 += __shfl_xor(f2, m, 64); f3 += __shfl_xor(f3, m, 64);
            f4 += __shfl_xor(f4, m, 64); f5 += __shfl_xor(f5, m, 64);
            f6 += __shfl_xor(f6, m, 64); f7 += __shfl_xor(f7, m, 64);
        }
        float nd = norm_dst[n];
        f0 *= nd; f1 *= nd; f2 *= nd; f3 *= nd;
        f4 *= nd; f5 *= nd; f6 *= nd; f7 *= nd;
        // GEMV: feature k lives on lane k>>3, component k&7
        float y = bj;
        #pragma unroll
        for (int k = 0; k < 64; ++k) {
            float comp = (k & 7) == 0 ? f0 : (k & 7) == 1 ? f1 : (k & 7) == 2 ? f2 :
                         (k & 7) == 3 ? f3 : (k & 7) == 4 ? f4 : (k & 7) == 5 ? f5 :
                         (k & 7) == 6 ? f6 : f7;
            float vk = __shfl(comp, k >> 3, 64);
            y = fmaf(vk, Wsh[k * 64 + lane], y);
        }
        y = fmaxf(y, 0.0f);
        if (apply_src) y *= norm_src[n];
        if (store_bf16) out_bf[(size_t)n * 64 + lane] = __float2bfloat16(y);
        else            out_f32[(size_t)n * 64 + lane] = y;
    }
}

// ---------- mean-pool + classifier head (one block per graph) ----------
__global__ void pool_kernel(const float* __restrict__ h, const int* __restrict__ gid, int N,
                            const float* __restrict__ Wc, const float* __restrict__ bc,
                            float* __restrict__ out, int n_graphs) {
    int g = blockIdx.x;
    int lo = 0, hi = N;
    while (lo < hi) { int mid = (lo + hi) >> 1; if (gid[mid] < g) lo = mid + 1; else hi = mid; }
    int start = lo;
    hi = N;
    while (lo < hi) { int mid = (lo + hi) >> 1; if (gid[mid] < g + 1) lo = mid + 1; else hi = mid; }
    int end = lo;
    int cnt = end - start;

    int lane = threadIdx.x & 63;
    int grp = threadIdx.x >> 6;
    float acc = 0.0f;
    for (int n = start + grp; n < end; n += 4) acc += h[(size_t)n * 64 + lane];

    __shared__ float sh[4][64];
    __shared__ float hrow[64];
    sh[grp][lane] = acc;
    __syncthreads();
    if (threadIdx.x < 64) {
        float s = sh[0][lane] + sh[1][lane] + sh[2][lane] + sh[3][lane];
        float m = s / fmaxf((float)cnt, 1.0f);
        hrow[lane] = m;
        out[(size_t)g * 64 + lane] = m;
    }
    __syncthreads();
    if (threadIdx.x < 10) {
        int c = threadIdx.x;
        float acc2 = bc[c];
        #pragma unroll
        for (int j = 0; j < 64; ++j) acc2 = fmaf(hrow[j], Wc[j * 10 + c], acc2);
        out[(size_t)n_graphs * 64 + (size_t)g * 10 + c] = acc2;
    }
}

extern "C" void kernel_launch(void* const* d_in, const int* in_sizes, int n_in,
                              void* d_out, int out_size, void* d_ws, size_t ws_size,
                              hipStream_t stream) {
    const int*   src = (const int*)d_in[0];
    const int*   dst = (const int*)d_in[1];
    const int*   gid = (const int*)d_in[2];
    const float* W1  = (const float*)d_in[4];
    const float* b1  = (const float*)d_in[5];
    const float* W2  = (const float*)d_in[6];
    const float* b2  = (const float*)d_in[7];
    const float* W3  = (const float*)d_in[8];
    const float* b3  = (const float*)d_in[9];
    const float* W4  = (const float*)d_in[10];
    const float* b4  = (const float*)d_in[11];
    const float* Wc  = (const float*)d_in[12];
    const float* bc  = (const float*)d_in[13];

    int E  = in_sizes[0];
    int N  = in_sizes[2];
    int ng = out_size / 74;

    // workspace carve-up (4-byte units); bufA and bf16 bufs 16B-aligned
    int* in_deg_i   = (int*)d_ws;              // N
    int* out_deg_i  = in_deg_i + N;            // N
    int* row_ptr    = out_deg_i + N;           // N+1
    int* cursor     = row_ptr + N + 1;         // N
    int* csr_src    = cursor + N;              // E
    int* block_sums = csr_src + E;             // 1024
    int* block_offs = block_sums + 1024;       // 1024
    float* norm_src = (float*)(block_offs + 1024); // N
    float* norm_dst = norm_src + N;            // N
    float* xs       = norm_dst + N;            // N
    float* a_buf    = xs + N;                  // N
    float* bufA     = (float*)(((uintptr_t)(a_buf + N) + 15) & ~(uintptr_t)15);  // 64N fp32
    __hip_bfloat16* hb1 = (__hip_bfloat16*)(bufA + 64 * (size_t)N);              // 64N bf16 (32N fl)
    __hip_bfloat16* hb2 = hb1 + 64 * (size_t)N;                                  // 64N bf16

    float* out_f = (float*)d_out;

    int NB = (N + 1023) / 1024;

    hipMemsetAsync(in_deg_i, 0, 2 * (size_t)N * sizeof(int), stream);
    deg_kernel<<<2048, 256, 0, stream>>>(src, dst, in_deg_i, out_deg_i, E, N);
    norm_kernel<<<(N + 255) / 256, 256, 0, stream>>>(in_deg_i, out_deg_i, norm_src, norm_dst, xs, N);

    scan_reduce<<<NB, 256, 0, stream>>>(in_deg_i, block_sums, N);
    scan_top<<<1, 1024, 0, stream>>>(block_sums, block_offs, NB, row_ptr, N);
    scan_apply<<<NB, 256, 0, stream>>>(in_deg_i, block_offs, row_ptr, cursor, N);
    fill_kernel<<<2048, 256, 0, stream>>>(src, dst, cursor, csr_src, E, N);

    agg1_kernel<<<(N + 255) / 256, 256, 0, stream>>>(row_ptr, csr_src, xs, norm_dst, a_buf, N);
    dense1_kernel<<<2048, 256, 0, stream>>>(a_buf, norm_src, W1, b1, hb1, N);

    // layers 2-4: bf16 gathers; layers 2-3 store bf16, layer 4 stores fp32
    conv_fused<<<2048, 256, 0, stream>>>(row_ptr, csr_src, (const uint4*)hb1, norm_dst, norm_src,
                                         W2, b2, nullptr, hb2, N, 1, 1);
    conv_fused<<<2048, 256, 0, stream>>>(row_ptr, csr_src, (const uint4*)hb2, norm_dst, norm_src,
                                         W3, b3, nullptr, hb1, N, 1, 1);
    conv_fused<<<2048, 256, 0, stream>>>(row_ptr, csr_src, (const uint4*)hb1, norm_dst, norm_src,
                                         W4, b4, bufA, nullptr, N, 0, 0);

    pool_kernel<<<ng, 256, 0, stream>>>(bufA, gid, N, Wc, bc, out_f, ng);
}

// Round 13
// 703.030 us; speedup vs baseline: 2.4403x; 1.1086x over previous
//
#include <hip/hip_runtime.h>
#include <hip/hip_bf16.h>

// GCN classifier: CSR pull-based aggregation + fused GEMV per layer.
// Round 13: (a) deg un-sliced again (R12 showed atomics execute memory-side:
// WRITE_SIZE identical under XCD slicing, which only added reads);
// (b) conv bf16 gather processes 2 edges per lane per iteration (R12 showed
// bf16 was time-neutral: halved bytes but also halved loads-in-flight);
// (c) pool split into partial (4 blocks/graph) + final.

// ---------- degree histogram (int atomics; atomic-count-bound) ----------
__global__ void deg_kernel(const int* __restrict__ src, const int* __restrict__ dst,
                           int* __restrict__ in_deg, int* __restrict__ out_deg, int E) {
    int stride = gridDim.x * blockDim.x;
    int E4 = E >> 2;
    const int4* src4 = (const int4*)src;
    const int4* dst4 = (const int4*)dst;
    for (int e = blockIdx.x * blockDim.x + threadIdx.x; e < E4; e += stride) {
        int4 s = src4[e], d = dst4[e];
        atomicAdd(&in_deg[d.x], 1); atomicAdd(&in_deg[d.y], 1);
        atomicAdd(&in_deg[d.z], 1); atomicAdd(&in_deg[d.w], 1);
        atomicAdd(&out_deg[s.x], 1); atomicAdd(&out_deg[s.y], 1);
        atomicAdd(&out_deg[s.z], 1); atomicAdd(&out_deg[s.w], 1);
    }
    int tid = blockIdx.x * blockDim.x + threadIdx.x;
    if (tid < (E & 3)) {
        int e = (E4 << 2) + tid;
        atomicAdd(&in_deg[dst[e]], 1);
        atomicAdd(&out_deg[src[e]], 1);
    }
}

// norms + layer-1 pre-scaled feature xs = in_deg * norm_src
__global__ void norm_kernel(const int* __restrict__ in_deg, const int* __restrict__ out_deg,
                            float* __restrict__ norm_src, float* __restrict__ norm_dst,
                            float* __restrict__ xs, int N) {
    int n = blockIdx.x * blockDim.x + threadIdx.x;
    if (n < N) {
        float id = (float)in_deg[n];
        float od = (float)out_deg[n];
        float ns = rsqrtf(fmaxf(od, 1.0f));
        norm_src[n] = ns;
        norm_dst[n] = rsqrtf(fmaxf(id, 1.0f));
        xs[n] = id * ns;
    }
}

// ---------- 3-kernel exclusive prefix scan of in_deg -> row_ptr ----------
__global__ void scan_reduce(const int* __restrict__ vals, int* __restrict__ block_sums, int N) {
    int t = threadIdx.x, b = blockIdx.x;
    int base = b * 1024 + t * 4;
    int s = 0;
    #pragma unroll
    for (int k = 0; k < 4; ++k) { int i = base + k; if (i < N) s += vals[i]; }
    for (int d = 32; d > 0; d >>= 1) s += __shfl_down(s, d, 64);
    __shared__ int wsum[4];
    if ((t & 63) == 0) wsum[t >> 6] = s;
    __syncthreads();
    if (t == 0) block_sums[b] = wsum[0] + wsum[1] + wsum[2] + wsum[3];
}

__global__ void scan_top(const int* __restrict__ block_sums, int* __restrict__ block_offs,
                         int NB, int* __restrict__ row_ptr, int N) {
    __shared__ int ts[1024];
    int t = threadIdx.x;
    int s = (t < NB) ? block_sums[t] : 0;
    ts[t] = s;
    __syncthreads();
    for (int d = 1; d < 1024; d <<= 1) {
        int x = (t >= d) ? ts[t - d] : 0;
        __syncthreads();
        ts[t] += x;
        __syncthreads();
    }
    block_offs[t] = ts[t] - s;
    if (t == 1023) row_ptr[N] = ts[1023];
}

__global__ void scan_apply(const int* __restrict__ vals, const int* __restrict__ block_offs,
                           int* __restrict__ row_ptr, int* __restrict__ cursor, int N) {
    __shared__ int ts[256];
    int t = threadIdx.x, b = blockIdx.x;
    int base = b * 1024 + t * 4;
    int v[4]; int s = 0;
    #pragma unroll
    for (int k = 0; k < 4; ++k) { int i = base + k; v[k] = (i < N) ? vals[i] : 0; s += v[k]; }
    ts[t] = s;
    __syncthreads();
    for (int d = 1; d < 256; d <<= 1) {
        int x = (t >= d) ? ts[t - d] : 0;
        __syncthreads();
        ts[t] += x;
        __syncthreads();
    }
    int ex = block_offs[b] + ts[t] - s;
    #pragma unroll
    for (int k = 0; k < 4; ++k) {
        int i = base + k;
        if (i < N) { row_ptr[i] = ex; cursor[i] = ex; }
        ex += v[k];
    }
}

// XCD-sliced CSR fill (plain stores DO merge in an XCD's L2 — keep slicing)
__global__ void fill_kernel(const int* __restrict__ src, const int* __restrict__ dst,
                            int* __restrict__ cursor, int* __restrict__ csr_src, int E, int N) {
    int slice = blockIdx.x & 7;
    int bs    = blockIdx.x >> 3;
    int nbs   = gridDim.x >> 3;
    int lo = (int)(((long long)slice * N) / 8);
    int hi = (slice == 7) ? N : (int)(((long long)(slice + 1) * N) / 8);
    int stride = nbs * blockDim.x;
    int E4 = E >> 2;
    const int4* src4 = (const int4*)src;
    const int4* dst4 = (const int4*)dst;
    for (int e = bs * blockDim.x + threadIdx.x; e < E4; e += stride) {
        int4 s = src4[e], d = dst4[e];
        if (d.x >= lo && d.x < hi) csr_src[atomicAdd(&cursor[d.x], 1)] = s.x;
        if (d.y >= lo && d.y < hi) csr_src[atomicAdd(&cursor[d.y], 1)] = s.y;
        if (d.z >= lo && d.z < hi) csr_src[atomicAdd(&cursor[d.z], 1)] = s.z;
        if (d.w >= lo && d.w < hi) csr_src[atomicAdd(&cursor[d.w], 1)] = s.w;
    }
    if (slice == 0 && bs == 0) {
        int tid = threadIdx.x;
        if (tid < (E & 3)) {
            int e = (E4 << 2) + tid;
            csr_src[atomicAdd(&cursor[dst[e]], 1)] = src[e];
        }
    }
}

// ---------- layer 1 (scalar feature) ----------
__global__ void agg1_kernel(const int* __restrict__ row_ptr, const int* __restrict__ csr_src,
                            const float* __restrict__ xs, const float* __restrict__ norm_dst,
                            float* __restrict__ a_buf, int N) {
    int n = blockIdx.x * blockDim.x + threadIdx.x;
    if (n < N) {
        int s0 = row_ptr[n], s1 = row_ptr[n + 1];
        float a = 0.0f;
        for (int i = s0; i < s1; ++i) a += xs[csr_src[i]];
        a_buf[n] = a * norm_dst[n];
    }
}

// layer-1 dense, output stored bf16 (feeds conv2's bf16 gather)
__global__ void dense1_kernel(const float* __restrict__ a_buf, const float* __restrict__ norm_src,
                              const float* __restrict__ W1, const float* __restrict__ b1,
                              __hip_bfloat16* __restrict__ out, int N) {
    int stride = gridDim.x * blockDim.x;
    int total = N * 64;
    for (int i = blockIdx.x * blockDim.x + threadIdx.x; i < total; i += stride) {
        int n = i >> 6, j = i & 63;
        float y = fmaxf(fmaf(a_buf[n], W1[j], b1[j]), 0.0f);
        out[i] = __float2bfloat16(y * norm_src[n]);
    }
}

// ---------- fused pull-aggregate (bf16 x, 2 edges/lane/iter) + GEMV ----------
// lane = 8*slot + q: slot (0..7) = edge slot, q (0..7) = uint4 index in the
// 128B bf16 row. Per iteration each lane loads rows of edges i AND i+8
// (stride 16) -> 16 independent 16B loads in flight per wave (R12 lesson:
// single-load bf16 halved MLP and was time-neutral vs fp32).
__global__ void conv_fused(const int* __restrict__ row_ptr, const int* __restrict__ csr_src,
                           const uint4* __restrict__ xb, const float* __restrict__ norm_dst,
                           const float* __restrict__ norm_src, const float* __restrict__ W,
                           const float* __restrict__ b, float* __restrict__ out_f32,
                           __hip_bfloat16* __restrict__ out_bf,
                           int N, int apply_src, int store_bf16) {
    __shared__ float Wsh[64 * 64];
    for (int i = threadIdx.x; i < 64 * 64; i += blockDim.x) Wsh[i] = W[i];
    __syncthreads();
    int lane = threadIdx.x & 63;
    int slot = lane >> 3;          // 0..7 edge slot
    int q    = lane & 7;           // uint4 index within row
    int grp  = threadIdx.x >> 6;
    int gpb  = blockDim.x >> 6;
    int gw   = blockIdx.x * gpb + grp;
    int nw   = gridDim.x * gpb;
    float bj = b[lane];
    for (int n = gw; n < N; n += nw) {
        int s0 = row_ptr[n], s1 = row_ptr[n + 1];
        float f0 = 0.f, f1 = 0.f, f2 = 0.f, f3 = 0.f,
              f4 = 0.f, f5 = 0.f, f6 = 0.f, f7 = 0.f;   // features 8q..8q+7
        for (int i = s0 + slot; i < s1; i += 16) {
            int sA = csr_src[i];
            int i2 = i + 8;
            uint4 uA = xb[(size_t)sA * 8 + q];
            uint4 uB = make_uint4(0u, 0u, 0u, 0u);       // bf16 zeros
            if (i2 < s1) {
                int sB = csr_src[i2];
                uB = xb[(size_t)sB * 8 + q];
            }
            f0 += __uint_as_float(uA.x << 16) + __uint_as_float(uB.x << 16);
            f1 += __uint_as_float(uA.x & 0xFFFF0000u) + __uint_as_float(uB.x & 0xFFFF0000u);
            f2 += __uint_as_float(uA.y << 16) + __uint_as_float(uB.y << 16);
            f3 += __uint_as_float(uA.y & 0xFFFF0000u) + __uint_as_float(uB.y & 0xFFFF0000u);
            f4 += __uint_as_float(uA.z << 16) + __uint_as_float(uB.z << 16);
            f5 += __uint_as_float(uA.z & 0xFFFF0000u) + __uint_as_float(uB.z & 0xFFFF0000u);
            f6 += __uint_as_float(uA.w << 16) + __uint_as_float(uB.w << 16);
            f7 += __uint_as_float(uA.w & 0xFFFF0000u) + __uint_as_float(uB.w & 0xFFFF0000u);
        }
        // reduce across the 8 edge slots (lanes with equal q): xor 8,16,32
        #pragma unroll
        for (int m = 8; m <= 32; m <<= 1) {
            f0 += __shfl_xor(f0, m, 64); f1 += __shfl_xor(f1, m, 64);
            f2 += __shfl_xor(f2, m, 64); f3 += __shfl_xor(f3, m, 64);
            f4 += __shfl_xor(f4, m, 64); f5 += __shfl_xor(f5, m, 64);
            f6 += __shfl_xor(f6, m, 64); f7 += __shfl_xor(f7, m, 64);
        }
        float nd = norm_dst[n];
        f0 *= nd; f1 *= nd; f2 *= nd; f3 *= nd;
        f4 *= nd; f5 *= nd; f6 *= nd; f7 *= nd;
        // GEMV: feature k lives on lane k>>3, component k&7
        float y = bj;
        #pragma unroll
        for (int k = 0; k < 64; ++k) {
            float comp = (k & 7) == 0 ? f0 : (k & 7) == 1 ? f1 : (k & 7) == 2 ? f2 :
                         (k & 7) == 3 ? f3 : (k & 7) == 4 ? f4 : (k & 7) == 5 ? f5 :
                         (k & 7) == 6 ? f6 : f7;
            float vk = __shfl(comp, k >> 3, 64);
            y = fmaf(vk, Wsh[k * 64 + lane], y);
        }
        y = fmaxf(y, 0.0f);
        if (apply_src) y *= norm_src[n];
        if (store_bf16) out_bf[(size_t)n * 64 + lane] = __float2bfloat16(y);
        else            out_f32[(size_t)n * 64 + lane] = y;
    }
}

// ---------- mean-pool: partial (4 blocks/graph) + final (head) ----------
__global__ void pool_partial(const float* __restrict__ h, const int* __restrict__ gid, int N,
                             float* __restrict__ partial) {
    int g  = blockIdx.x >> 2;
    int qt = blockIdx.x & 3;
    int lo = 0, hi = N;
    while (lo < hi) { int mid = (lo + hi) >> 1; if (gid[mid] < g) lo = mid + 1; else hi = mid; }
    int start = lo;
    hi = N;
    while (lo < hi) { int mid = (lo + hi) >> 1; if (gid[mid] < g + 1) lo = mid + 1; else hi = mid; }
    int end = lo;
    int cnt = end - start;
    int qlo = start + (int)(((long long)cnt * qt) / 4);
    int qhi = start + (int)(((long long)cnt * (qt + 1)) / 4);

    int lane = threadIdx.x & 63;
    int grp  = threadIdx.x >> 6;
    float acc = 0.0f;
    for (int n = qlo + grp; n < qhi; n += 4) acc += h[(size_t)n * 64 + lane];

    __shared__ float sh[4][64];
    sh[grp][lane] = acc;
    __syncthreads();
    if (threadIdx.x < 64)
        partial[(size_t)blockIdx.x * 64 + lane] =
            sh[0][lane] + sh[1][lane] + sh[2][lane] + sh[3][lane];
}

__global__ void pool_final(const float* __restrict__ partial, const int* __restrict__ gid, int N,
                           const float* __restrict__ Wc, const float* __restrict__ bc,
                           float* __restrict__ out, int n_graphs) {
    int g = blockIdx.x;              // 64 threads per block
    int lo = 0, hi = N;
    while (lo < hi) { int mid = (lo + hi) >> 1; if (gid[mid] < g) lo = mid + 1; else hi = mid; }
    int start = lo;
    hi = N;
    while (lo < hi) { int mid = (lo + hi) >> 1; if (gid[mid] < g + 1) lo = mid + 1; else hi = mid; }
    int cnt = lo - start;

    int lane = threadIdx.x;
    __shared__ float hrow[64];
    float s = partial[(size_t)(g * 4 + 0) * 64 + lane] + partial[(size_t)(g * 4 + 1) * 64 + lane]
            + partial[(size_t)(g * 4 + 2) * 64 + lane] + partial[(size_t)(g * 4 + 3) * 64 + lane];
    float m = s / fmaxf((float)cnt, 1.0f);
    hrow[lane] = m;
    out[(size_t)g * 64 + lane] = m;
    __syncthreads();
    if (lane < 10) {
        float acc2 = bc[lane];
        #pragma unroll
        for (int j = 0; j < 64; ++j) acc2 = fmaf(hrow[j], Wc[j * 10 + lane], acc2);
        out[(size_t)n_graphs * 64 + (size_t)g * 10 + lane] = acc2;
    }
}

extern "C" void kernel_launch(void* const* d_in, const int* in_sizes, int n_in,
                              void* d_out, int out_size, void* d_ws, size_t ws_size,
                              hipStream_t stream) {
    const int*   src = (const int*)d_in[0];
    const int*   dst = (const int*)d_in[1];
    const int*   gid = (const int*)d_in[2];
    const float* W1  = (const float*)d_in[4];
    const float* b1  = (const float*)d_in[5];
    const float* W2  = (const float*)d_in[6];
    const float* b2  = (const float*)d_in[7];
    const float* W3  = (const float*)d_in[8];
    const float* b3  = (const float*)d_in[9];
    const float* W4  = (const float*)d_in[10];
    const float* b4  = (const float*)d_in[11];
    const float* Wc  = (const float*)d_in[12];
    const float* bc  = (const float*)d_in[13];

    int E  = in_sizes[0];
    int N  = in_sizes[2];
    int ng = out_size / 74;

    // workspace carve-up (4-byte units)
    int* in_deg_i   = (int*)d_ws;              // N
    int* out_deg_i  = in_deg_i + N;            // N
    int* row_ptr    = out_deg_i + N;           // N+1
    int* cursor     = row_ptr + N + 1;         // N
    int* csr_src    = cursor + N;              // E
    int* block_sums = csr_src + E;             // 1024
    int* block_offs = block_sums + 1024;       // 1024
    float* norm_src = (float*)(block_offs + 1024); // N
    float* norm_dst = norm_src + N;            // N
    float* xs       = norm_dst + N;            // N
    float* a_buf    = xs + N;                  // N
    float* bufA     = (float*)(((uintptr_t)(a_buf + N) + 15) & ~(uintptr_t)15);  // 64N fp32
    __hip_bfloat16* hb1 = (__hip_bfloat16*)(bufA + 64 * (size_t)N);              // 64N bf16
    __hip_bfloat16* hb2 = hb1 + 64 * (size_t)N;                                  // 64N bf16
    float* partial  = (float*)(hb2 + 64 * (size_t)N);                            // ng*4*64

    float* out_f = (float*)d_out;

    int NB = (N + 1023) / 1024;

    hipMemsetAsync(in_deg_i, 0, 2 * (size_t)N * sizeof(int), stream);
    deg_kernel<<<2048, 256, 0, stream>>>(src, dst, in_deg_i, out_deg_i, E);
    norm_kernel<<<(N + 255) / 256, 256, 0, stream>>>(in_deg_i, out_deg_i, norm_src, norm_dst, xs, N);

    scan_reduce<<<NB, 256, 0, stream>>>(in_deg_i, block_sums, N);
    scan_top<<<1, 1024, 0, stream>>>(block_sums, block_offs, NB, row_ptr, N);
    scan_apply<<<NB, 256, 0, stream>>>(in_deg_i, block_offs, row_ptr, cursor, N);
    fill_kernel<<<2048, 256, 0, stream>>>(src, dst, cursor, csr_src, E, N);

    agg1_kernel<<<(N + 255) / 256, 256, 0, stream>>>(row_ptr, csr_src, xs, norm_dst, a_buf, N);
    dense1_kernel<<<2048, 256, 0, stream>>>(a_buf, norm_src, W1, b1, hb1, N);

    // layers 2-4: bf16 gathers, 2 edges/lane/iter; layers 2-3 store bf16
    conv_fused<<<2048, 256, 0, stream>>>(row_ptr, csr_src, (const uint4*)hb1, norm_dst, norm_src,
                                         W2, b2, nullptr, hb2, N, 1, 1);
    conv_fused<<<2048, 256, 0, stream>>>(row_ptr, csr_src, (const uint4*)hb2, norm_dst, norm_src,
                                         W3, b3, nullptr, hb1, N, 1, 1);
    conv_fused<<<2048, 256, 0, stream>>>(row_ptr, csr_src, (const uint4*)hb1, norm_dst, norm_src,
                                         W4, b4, bufA, nullptr, N, 0, 0);

    pool_partial<<<ng * 4, 256, 0, stream>>>(bufA, gid, N, partial);
    pool_final<<<ng, 64, 0, stream>>>(partial, gid, N, Wc, bc, out_f, ng);
}

// Round 15
// 601.302 us; speedup vs baseline: 2.8531x; 1.1692x over previous
//
#include <hip/hip_runtime.h>
#include <hip/hip_bf16.h>

// GCN classifier: CSR pull-based aggregation + fused GEMV per layer.
// Round 14 (resubmit): deg_kernel replaced by LDS-privatized hist_kernel.
// R13 counters proved deg is atomic-transaction-bound: WRITE_SIZE 99.8 MB =
// 3.2M atomics x 32B (memory-side execution, L2 can't merge them — R12's
// slicing null result). hist_kernel does LDS atomics only (16 node-slices x
// 8 edge partitions, 50KB LDS/block), flushes partials with plain stores,
// and norm_kernel reduces the 8 partials per node. Zero global atomics.

#define HSLICES 16
#define HBPS    8
#define HCAP    6272   // >= ceil(N/HSLICES) for N=100000 (6250), 16B-aligned

// ---------- LDS-histogram degree count ----------
// grid = HSLICES*HBPS = 128 blocks, 1024 threads. slice = blockIdx>>3 (node
// range), bp = blockIdx&7 (edge partition == XCD via round-robin dispatch, so
// each XCD re-reads only its own 1.6MB partition from its L2).
__global__ __launch_bounds__(1024) void hist_kernel(const int* __restrict__ src,
                                                    const int* __restrict__ dst,
                                                    int* __restrict__ partials, int E, int N) {
    __shared__ int lin[HCAP];
    __shared__ int lout[HCAP];
    int s  = blockIdx.x >> 3;
    int bp = blockIdx.x & 7;
    int lo  = (int)(((long long)s * N) / HSLICES);
    int hi  = (int)(((long long)(s + 1) * N) / HSLICES);
    int rng = hi - lo;
    for (int i = threadIdx.x; i < HCAP; i += 1024) { lin[i] = 0; lout[i] = 0; }
    __syncthreads();

    int E4 = E >> 2;
    int P4 = (E4 + HBPS - 1) / HBPS;
    int p0 = bp * P4;
    int p1 = p0 + P4; if (p1 > E4) p1 = E4;
    const int4* src4 = (const int4*)src;
    const int4* dst4 = (const int4*)dst;
    for (int e = p0 + threadIdx.x; e < p1; e += 1024) {
        int4 sv = src4[e], dv = dst4[e];
        if ((unsigned)(dv.x - lo) < (unsigned)rng) atomicAdd(&lin[dv.x - lo], 1);
        if ((unsigned)(dv.y - lo) < (unsigned)rng) atomicAdd(&lin[dv.y - lo], 1);
        if ((unsigned)(dv.z - lo) < (unsigned)rng) atomicAdd(&lin[dv.z - lo], 1);
        if ((unsigned)(dv.w - lo) < (unsigned)rng) atomicAdd(&lin[dv.w - lo], 1);
        if ((unsigned)(sv.x - lo) < (unsigned)rng) atomicAdd(&lout[sv.x - lo], 1);
        if ((unsigned)(sv.y - lo) < (unsigned)rng) atomicAdd(&lout[sv.y - lo], 1);
        if ((unsigned)(sv.z - lo) < (unsigned)rng) atomicAdd(&lout[sv.z - lo], 1);
        if ((unsigned)(sv.w - lo) < (unsigned)rng) atomicAdd(&lout[sv.w - lo], 1);
    }
    if (bp == HBPS - 1) {           // scalar tail (E not multiple of 4)
        for (int e = (E4 << 2) + threadIdx.x; e < E; e += 1024) {
            int d = dst[e], sc = src[e];
            if ((unsigned)(d - lo) < (unsigned)rng) atomicAdd(&lin[d - lo], 1);
            if ((unsigned)(sc - lo) < (unsigned)rng) atomicAdd(&lout[sc - lo], 1);
        }
    }
    __syncthreads();
    int base = (s * HBPS + bp) * (2 * HCAP);
    for (int i = threadIdx.x; i < rng; i += 1024) {
        partials[base + i]        = lin[i];
        partials[base + HCAP + i] = lout[i];
    }
}

// fused: reduce 8 partials/node -> in_deg (int, feeds scan), norms, xs
__global__ void norm_kernel(const int* __restrict__ partials, int* __restrict__ in_deg,
                            float* __restrict__ norm_src, float* __restrict__ norm_dst,
                            float* __restrict__ xs, int N) {
    int n = blockIdx.x * blockDim.x + threadIdx.x;
    if (n >= N) return;
    int s  = (int)(((long long)n * HSLICES) / N);
    int lo = (int)(((long long)s * N) / HSLICES);
    int l  = n - lo;
    int id = 0, od = 0;
    #pragma unroll
    for (int bp = 0; bp < HBPS; ++bp) {
        int base = (s * HBPS + bp) * (2 * HCAP);
        id += partials[base + l];
        od += partials[base + HCAP + l];
    }
    in_deg[n] = id;
    float idf = (float)id, odf = (float)od;
    float ns = rsqrtf(fmaxf(odf, 1.0f));
    norm_src[n] = ns;
    norm_dst[n] = rsqrtf(fmaxf(idf, 1.0f));
    xs[n] = idf * ns;
}

// ---------- 3-kernel exclusive prefix scan of in_deg -> row_ptr ----------
__global__ void scan_reduce(const int* __restrict__ vals, int* __restrict__ block_sums, int N) {
    int t = threadIdx.x, b = blockIdx.x;
    int base = b * 1024 + t * 4;
    int s = 0;
    #pragma unroll
    for (int k = 0; k < 4; ++k) { int i = base + k; if (i < N) s += vals[i]; }
    for (int d = 32; d > 0; d >>= 1) s += __shfl_down(s, d, 64);
    __shared__ int wsum[4];
    if ((t & 63) == 0) wsum[t >> 6] = s;
    __syncthreads();
    if (t == 0) block_sums[b] = wsum[0] + wsum[1] + wsum[2] + wsum[3];
}

__global__ void scan_top(const int* __restrict__ block_sums, int* __restrict__ block_offs,
                         int NB, int* __restrict__ row_ptr, int N) {
    __shared__ int ts[1024];
    int t = threadIdx.x;
    int s = (t < NB) ? block_sums[t] : 0;
    ts[t] = s;
    __syncthreads();
    for (int d = 1; d < 1024; d <<= 1) {
        int x = (t >= d) ? ts[t - d] : 0;
        __syncthreads();
        ts[t] += x;
        __syncthreads();
    }
    block_offs[t] = ts[t] - s;
    if (t == 1023) row_ptr[N] = ts[1023];
}

__global__ void scan_apply(const int* __restrict__ vals, const int* __restrict__ block_offs,
                           int* __restrict__ row_ptr, int* __restrict__ cursor, int N) {
    __shared__ int ts[256];
    int t = threadIdx.x, b = blockIdx.x;
    int base = b * 1024 + t * 4;
    int v[4]; int s = 0;
    #pragma unroll
    for (int k = 0; k < 4; ++k) { int i = base + k; v[k] = (i < N) ? vals[i] : 0; s += v[k]; }
    ts[t] = s;
    __syncthreads();
    for (int d = 1; d < 256; d <<= 1) {
        int x = (t >= d) ? ts[t - d] : 0;
        __syncthreads();
        ts[t] += x;
        __syncthreads();
    }
    int ex = block_offs[b] + ts[t] - s;
    #pragma unroll
    for (int k = 0; k < 4; ++k) {
        int i = base + k;
        if (i < N) { row_ptr[i] = ex; cursor[i] = ex; }
        ex += v[k];
    }
}

// XCD-sliced CSR fill (plain stores DO merge in an XCD's L2 — keep slicing)
__global__ void fill_kernel(const int* __restrict__ src, const int* __restrict__ dst,
                            int* __restrict__ cursor, int* __restrict__ csr_src, int E, int N) {
    int slice = blockIdx.x & 7;
    int bs    = blockIdx.x >> 3;
    int nbs   = gridDim.x >> 3;
    int lo = (int)(((long long)slice * N) / 8);
    int hi = (slice == 7) ? N : (int)(((long long)(slice + 1) * N) / 8);
    int stride = nbs * blockDim.x;
    int E4 = E >> 2;
    const int4* src4 = (const int4*)src;
    const int4* dst4 = (const int4*)dst;
    for (int e = bs * blockDim.x + threadIdx.x; e < E4; e += stride) {
        int4 s = src4[e], d = dst4[e];
        if (d.x >= lo && d.x < hi) csr_src[atomicAdd(&cursor[d.x], 1)] = s.x;
        if (d.y >= lo && d.y < hi) csr_src[atomicAdd(&cursor[d.y], 1)] = s.y;
        if (d.z >= lo && d.z < hi) csr_src[atomicAdd(&cursor[d.z], 1)] = s.z;
        if (d.w >= lo && d.w < hi) csr_src[atomicAdd(&cursor[d.w], 1)] = s.w;
    }
    if (slice == 0 && bs == 0) {
        int tid = threadIdx.x;
        if (tid < (E & 3)) {
            int e = (E4 << 2) + tid;
            csr_src[atomicAdd(&cursor[dst[e]], 1)] = src[e];
        }
    }
}

// ---------- layer 1 (scalar feature) ----------
__global__ void agg1_kernel(const int* __restrict__ row_ptr, const int* __restrict__ csr_src,
                            const float* __restrict__ xs, const float* __restrict__ norm_dst,
                            float* __restrict__ a_buf, int N) {
    int n = blockIdx.x * blockDim.x + threadIdx.x;
    if (n < N) {
        int s0 = row_ptr[n], s1 = row_ptr[n + 1];
        float a = 0.0f;
        for (int i = s0; i < s1; ++i) a += xs[csr_src[i]];
        a_buf[n] = a * norm_dst[n];
    }
}

// layer-1 dense, output stored bf16 (feeds conv2's bf16 gather)
__global__ void dense1_kernel(const float* __restrict__ a_buf, const float* __restrict__ norm_src,
                              const float* __restrict__ W1, const float* __restrict__ b1,
                              __hip_bfloat16* __restrict__ out, int N) {
    int stride = gridDim.x * blockDim.x;
    int total = N * 64;
    for (int i = blockIdx.x * blockDim.x + threadIdx.x; i < total; i += stride) {
        int n = i >> 6, j = i & 63;
        float y = fmaxf(fmaf(a_buf[n], W1[j], b1[j]), 0.0f);
        out[i] = __float2bfloat16(y * norm_src[n]);
    }
}

// ---------- fused pull-aggregate (bf16 x, 2 edges/lane/iter) + GEMV ----------
__global__ void conv_fused(const int* __restrict__ row_ptr, const int* __restrict__ csr_src,
                           const uint4* __restrict__ xb, const float* __restrict__ norm_dst,
                           const float* __restrict__ norm_src, const float* __restrict__ W,
                           const float* __restrict__ b, float* __restrict__ out_f32,
                           __hip_bfloat16* __restrict__ out_bf,
                           int N, int apply_src, int store_bf16) {
    __shared__ float Wsh[64 * 64];
    for (int i = threadIdx.x; i < 64 * 64; i += blockDim.x) Wsh[i] = W[i];
    __syncthreads();
    int lane = threadIdx.x & 63;
    int slot = lane >> 3;          // 0..7 edge slot
    int q    = lane & 7;           // uint4 index within row
    int grp  = threadIdx.x >> 6;
    int gpb  = blockDim.x >> 6;
    int gw   = blockIdx.x * gpb + grp;
    int nw   = gridDim.x * gpb;
    float bj = b[lane];
    for (int n = gw; n < N; n += nw) {
        int s0 = row_ptr[n], s1 = row_ptr[n + 1];
        float f0 = 0.f, f1 = 0.f, f2 = 0.f, f3 = 0.f,
              f4 = 0.f, f5 = 0.f, f6 = 0.f, f7 = 0.f;   // features 8q..8q+7
        for (int i = s0 + slot; i < s1; i += 16) {
            int sA = csr_src[i];
            int i2 = i + 8;
            uint4 uA = xb[(size_t)sA * 8 + q];
            uint4 uB = make_uint4(0u, 0u, 0u, 0u);       // bf16 zeros
            if (i2 < s1) {
                int sB = csr_src[i2];
                uB = xb[(size_t)sB * 8 + q];
            }
            f0 += __uint_as_float(uA.x << 16) + __uint_as_float(uB.x << 16);
            f1 += __uint_as_float(uA.x & 0xFFFF0000u) + __uint_as_float(uB.x & 0xFFFF0000u);
            f2 += __uint_as_float(uA.y << 16) + __uint_as_float(uB.y << 16);
            f3 += __uint_as_float(uA.y & 0xFFFF0000u) + __uint_as_float(uB.y & 0xFFFF0000u);
            f4 += __uint_as_float(uA.z << 16) + __uint_as_float(uB.z << 16);
            f5 += __uint_as_float(uA.z & 0xFFFF0000u) + __uint_as_float(uB.z & 0xFFFF0000u);
            f6 += __uint_as_float(uA.w << 16) + __uint_as_float(uB.w << 16);
            f7 += __uint_as_float(uA.w & 0xFFFF0000u) + __uint_as_float(uB.w & 0xFFFF0000u);
        }
        #pragma unroll
        for (int m = 8; m <= 32; m <<= 1) {
            f0 += __shfl_xor(f0, m, 64); f1 += __shfl_xor(f1, m, 64);
            f2 += __shfl_xor(f2, m, 64); f3 += __shfl_xor(f3, m, 64);
            f4 += __shfl_xor(f4, m, 64); f5 += __shfl_xor(f5, m, 64);
            f6 += __shfl_xor(f6, m, 64); f7 += __shfl_xor(f7, m, 64);
        }
        float nd = norm_dst[n];
        f0 *= nd; f1 *= nd; f2 *= nd; f3 *= nd;
        f4 *= nd; f5 *= nd; f6 *= nd; f7 *= nd;
        float y = bj;
        #pragma unroll
        for (int k = 0; k < 64; ++k) {
            float comp = (k & 7) == 0 ? f0 : (k & 7) == 1 ? f1 : (k & 7) == 2 ? f2 :
                         (k & 7) == 3 ? f3 : (k & 7) == 4 ? f4 : (k & 7) == 5 ? f5 :
                         (k & 7) == 6 ? f6 : f7;
            float vk = __shfl(comp, k >> 3, 64);
            y = fmaf(vk, Wsh[k * 64 + lane], y);
        }
        y = fmaxf(y, 0.0f);
        if (apply_src) y *= norm_src[n];
        if (store_bf16) out_bf[(size_t)n * 64 + lane] = __float2bfloat16(y);
        else            out_f32[(size_t)n * 64 + lane] = y;
    }
}

// ---------- mean-pool: partial (4 blocks/graph) + final (head) ----------
__global__ void pool_partial(const float* __restrict__ h, const int* __restrict__ gid, int N,
                             float* __restrict__ partial) {
    int g  = blockIdx.x >> 2;
    int qt = blockIdx.x & 3;
    int lo = 0, hi = N;
    while (lo < hi) { int mid = (lo + hi) >> 1; if (gid[mid] < g) lo = mid + 1; else hi = mid; }
    int start = lo;
    hi = N;
    while (lo < hi) { int mid = (lo + hi) >> 1; if (gid[mid] < g + 1) lo = mid + 1; else hi = mid; }
    int end = lo;
    int cnt = end - start;
    int qlo = start + (int)(((long long)cnt * qt) / 4);
    int qhi = start + (int)(((long long)cnt * (qt + 1)) / 4);

    int lane = threadIdx.x & 63;
    int grp  = threadIdx.x >> 6;
    float acc = 0.0f;
    for (int n = qlo + grp; n < qhi; n += 4) acc += h[(size_t)n * 64 + lane];

    __shared__ float sh[4][64];
    sh[grp][lane] = acc;
    __syncthreads();
    if (threadIdx.x < 64)
        partial[(size_t)blockIdx.x * 64 + lane] =
            sh[0][lane] + sh[1][lane] + sh[2][lane] + sh[3][lane];
}

__global__ void pool_final(const float* __restrict__ partial, const int* __restrict__ gid, int N,
                           const float* __restrict__ Wc, const float* __restrict__ bc,
                           float* __restrict__ out, int n_graphs) {
    int g = blockIdx.x;              // 64 threads per block
    int lo = 0, hi = N;
    while (lo < hi) { int mid = (lo + hi) >> 1; if (gid[mid] < g) lo = mid + 1; else hi = mid; }
    int start = lo;
    hi = N;
    while (lo < hi) { int mid = (lo + hi) >> 1; if (gid[mid] < g + 1) lo = mid + 1; else hi = mid; }
    int cnt = lo - start;

    int lane = threadIdx.x;
    __shared__ float hrow[64];
    float s = partial[(size_t)(g * 4 + 0) * 64 + lane] + partial[(size_t)(g * 4 + 1) * 64 + lane]
            + partial[(size_t)(g * 4 + 2) * 64 + lane] + partial[(size_t)(g * 4 + 3) * 64 + lane];
    float m = s / fmaxf((float)cnt, 1.0f);
    hrow[lane] = m;
    out[(size_t)g * 64 + lane] = m;
    __syncthreads();
    if (lane < 10) {
        float acc2 = bc[lane];
        #pragma unroll
        for (int j = 0; j < 64; ++j) acc2 = fmaf(hrow[j], Wc[j * 10 + lane], acc2);
        out[(size_t)n_graphs * 64 + (size_t)g * 10 + lane] = acc2;
    }
}

extern "C" void kernel_launch(void* const* d_in, const int* in_sizes, int n_in,
                              void* d_out, int out_size, void* d_ws, size_t ws_size,
                              hipStream_t stream) {
    const int*   src = (const int*)d_in[0];
    const int*   dst = (const int*)d_in[1];
    const int*   gid = (const int*)d_in[2];
    const float* W1  = (const float*)d_in[4];
    const float* b1  = (const float*)d_in[5];
    const float* W2  = (const float*)d_in[6];
    const float* b2  = (const float*)d_in[7];
    const float* W3  = (const float*)d_in[8];
    const float* b3  = (const float*)d_in[9];
    const float* W4  = (const float*)d_in[10];
    const float* b4  = (const float*)d_in[11];
    const float* Wc  = (const float*)d_in[12];
    const float* bc  = (const float*)d_in[13];

    int E  = in_sizes[0];
    int N  = in_sizes[2];
    int ng = out_size / 74;

    // workspace carve-up (4-byte units)
    int* in_deg_i   = (int*)d_ws;              // N
    int* row_ptr    = in_deg_i + N;            // N+1
    int* cursor     = row_ptr + N + 1;         // N
    int* csr_src    = cursor + N;              // E
    int* block_sums = csr_src + E;             // 1024
    int* block_offs = block_sums + 1024;       // 1024
    float* norm_src = (float*)(block_offs + 1024); // N
    float* norm_dst = norm_src + N;            // N
    float* xs       = norm_dst + N;            // N
    float* a_buf    = xs + N;                  // N
    float* bufA     = (float*)(((uintptr_t)(a_buf + N) + 15) & ~(uintptr_t)15);  // 64N fp32
    __hip_bfloat16* hb1 = (__hip_bfloat16*)(bufA + 64 * (size_t)N);              // 64N bf16
    __hip_bfloat16* hb2 = hb1 + 64 * (size_t)N;                                  // 64N bf16
    float* partial  = (float*)(hb2 + 64 * (size_t)N);                            // ng*4*64
    // hist partials alias bufA (6.4 MB < 25.6 MB; bufA first written by
    // layer-4 conv, long after norm_kernel consumed the partials)
    int* hpart      = (int*)bufA;              // HSLICES*HBPS*2*HCAP

    float* out_f = (float*)d_out;

    int NB = (N + 1023) / 1024;

    hist_kernel<<<HSLICES * HBPS, 1024, 0, stream>>>(src, dst, hpart, E, N);
    norm_kernel<<<(N + 255) / 256, 256, 0, stream>>>(hpart, in_deg_i, norm_src, norm_dst, xs, N);

    scan_reduce<<<NB, 256, 0, stream>>>(in_deg_i, block_sums, N);
    scan_top<<<1, 1024, 0, stream>>>(block_sums, block_offs, NB, row_ptr, N);
    scan_apply<<<NB, 256, 0, stream>>>(in_deg_i, block_offs, row_ptr, cursor, N);
    fill_kernel<<<2048, 256, 0, stream>>>(src, dst, cursor, csr_src, E, N);

    agg1_kernel<<<(N + 255) / 256, 256, 0, stream>>>(row_ptr, csr_src, xs, norm_dst, a_buf, N);
    dense1_kernel<<<2048, 256, 0, stream>>>(a_buf, norm_src, W1, b1, hb1, N);

    conv_fused<<<2048, 256, 0, stream>>>(row_ptr, csr_src, (const uint4*)hb1, norm_dst, norm_src,
                                         W2, b2, nullptr, hb2, N, 1, 1);
    conv_fused<<<2048, 256, 0, stream>>>(row_ptr, csr_src, (const uint4*)hb2, norm_dst, norm_src,
                                         W3, b3, nullptr, hb1, N, 1, 1);
    conv_fused<<<2048, 256, 0, stream>>>(row_ptr, csr_src, (const uint4*)hb1, norm_dst, norm_src,
                                         W4, b4, bufA, nullptr, N, 0, 0);

    pool_partial<<<ng * 4, 256, 0, stream>>>(bufA, gid, N, partial);
    pool_final<<<ng, 64, 0, stream>>>(partial, gid, N, Wc, bc, out_f, ng);
}